// Round 5
// baseline (1174.480 us; speedup 1.0000x reference)
//
#include <hip/hip_runtime.h>
#include <hip/hip_bf16.h>
#include <stdint.h>

// Problem constants
#define E_  1024
#define H_  16
#define D_  64
#define T_  2048
#define B_  2

typedef unsigned short u16;
typedef unsigned char u8;
typedef __attribute__((ext_vector_type(8))) __bf16 bf16x8;
typedef __attribute__((ext_vector_type(4))) float f32x4;
typedef __attribute__((ext_vector_type(8))) u16 u16x8;
typedef __attribute__((ext_vector_type(4))) u16 u16x4;

__device__ __forceinline__ float bf2f(u16 u) {
  union { uint32_t u32; float f; } x; x.u32 = ((uint32_t)u) << 16; return x.f;
}
__device__ __forceinline__ u16 f2bf(float v) {
  union { float f; uint32_t u; } x; x.f = v;
  uint32_t r = x.u + 0x7fffu + ((x.u >> 16) & 1u);  // round-to-nearest-even
  return (u16)(r >> 16);
}
__device__ __forceinline__ void async16(const void* g, void* l) {
  __builtin_amdgcn_global_load_lds(
      (const __attribute__((address_space(1))) void*)g,
      (__attribute__((address_space(3))) void*)l, 16, 0, 0);
}

// ---------------- dtype detection ----------------
// flags[0]: 1 = float inputs are f32, 0 = bf16 (exponent-field statistics of
// even u16 halves). flags[1]: 1 = mask is int32, 0 = packed bytes.
__global__ __launch_bounds__(256) void detect_kernel(const u16* __restrict__ xu,
                                                     const void* __restrict__ mp,
                                                     int* __restrict__ flags) {
  __shared__ int cnt[2];
  const int tid = threadIdx.x;
  if (tid < 2) cnt[tid] = 0;
  __syncthreads();
  int c = 0;
  for (int i = tid; i < 4096; i += 256) {
    u16 u = xu[2 * i];
    int e = (u >> 7) & 0xFF;
    if (e != 0 && (e <= 0x40 || e >= 0xC0)) c++;
  }
  atomicAdd(&cnt[0], c);
  int m = 0;
  const unsigned int* mi = (const unsigned int*)mp;
  for (int i = tid; i < 1024; i += 256)
    if (mi[i] > 1u) m++;
  atomicAdd(&cnt[1], m);
  __syncthreads();
  if (tid == 0) {
    flags[0] = (cnt[0] > 409) ? 1 : 0;
    flags[1] = (cnt[1] == 0) ? 1 : 0;
  }
}

// canonicalize a float tensor (f32 or bf16 per flags[0]) to bf16
__global__ __launch_bounds__(256) void convf_kernel(const void* __restrict__ src,
                                                    u16* __restrict__ dst, int n,
                                                    const int* __restrict__ flags) {
  int i = (blockIdx.x * 256 + threadIdx.x) * 8;
  if (i >= n) return;
  if (flags[0]) {
    const float* s = (const float*)src;
    u16x8 o;
#pragma unroll
    for (int j = 0; j < 8; ++j) o[j] = f2bf(s[i + j]);
    *(u16x8*)(dst + i) = o;
  } else {
    *(u16x8*)(dst + i) = *(const u16x8*)((const u16*)src + i);
  }
}

// mask -> additive bias table (0 keep, -1e5 drop), f32
__global__ __launch_bounds__(256) void maskbias_kernel(const void* __restrict__ mp,
                                                       float* __restrict__ mbg,
                                                       const int* __restrict__ flags) {
  int i = blockIdx.x * 256 + threadIdx.x;  // 4096 total
  int keep = flags[1] ? (((const int*)mp)[i] != 0) : (((const u8*)mp)[i] != 0);
  mbg[i] = keep ? 0.f : -1e5f;
}

// ---------------- weight transpose: WT[e][i] = W[i][e] ----------------
__global__ __launch_bounds__(256) void wt_kernel(const u16* __restrict__ W,
                                                 u16* __restrict__ WT) {
  __shared__ __align__(16) u16 tile[64][65];
  const int bx = blockIdx.x * 64;
  const int by = blockIdx.y * 64;
  const int t = threadIdx.x;
#pragma unroll
  for (int p = 0; p < 2; ++p) {
    int row = p * 32 + (t >> 3);
    int ch = t & 7;
    u16x8 v = *(const u16x8*)(W + (size_t)(by + row) * E_ + bx + ch * 8);
#pragma unroll
    for (int j = 0; j < 8; ++j) tile[row][ch * 8 + j] = v[j];
  }
  __syncthreads();
#pragma unroll
  for (int p = 0; p < 2; ++p) {
    int orow = p * 32 + (t >> 3);
    int ch = t & 7;
    u16x8 v;
#pragma unroll
    for (int j = 0; j < 8; ++j) v[j] = tile[ch * 8 + j][orow];
    *(u16x8*)(WT + (size_t)(bx + orow) * E_ + by + ch * 8) = v;
  }
}

// ---------------- GEMM: C[r][e] = sum_i A[r][i] * BT[e][i] + bias[e] --------
// OUTMODE 0: write (B,H,T,D) bf16   (Q, K)
// OUTMODE 1: write (B,H,D,T) bf16   (V transposed, packed 8B stores)
// OUTMODE 2: write row-major FLOAT32 (final output)
template <int OUTMODE>
__global__ __launch_bounds__(256, 2) void gemm_kernel(
    const u16* __restrict__ A, const u16* __restrict__ BTm,
    const u16* __restrict__ bias, void* __restrict__ outv) {
  __shared__ __align__(16) u16 As[128 * 64];
  __shared__ __align__(16) u16 Bs[128 * 64];
  const int tid = threadIdx.x, lane = tid & 63, wid = tid >> 6;
  const int wm = wid >> 1, wn = wid & 1;
  const int l15 = lane & 15, lg = lane >> 4;
  const int r0 = blockIdx.x * 128, c0 = blockIdx.y * 128;
  f32x4 acc[4][4] = {};

  for (int k0 = 0; k0 < E_; k0 += 64) {
    __syncthreads();
#pragma unroll
    for (int i = 0; i < 4; ++i) {
      int row = i * 32 + (tid >> 3);
      int g = (tid & 7) ^ (row & 7);  // inverse-swizzled global source (T2)
      async16(A + (size_t)(r0 + row) * E_ + k0 + g * 8,
              (char*)As + i * 4096 + tid * 16);
      async16(BTm + (size_t)(c0 + row) * E_ + k0 + g * 8,
              (char*)Bs + i * 4096 + tid * 16);
    }
    __syncthreads();
#pragma unroll
    for (int kk = 0; kk < 2; ++kk) {
      bf16x8 af[4], bfr[4];
#pragma unroll
      for (int mt = 0; mt < 4; ++mt) {
        int rowa = wm * 64 + mt * 16 + l15;
        int sa = (kk * 4 + lg) ^ (rowa & 7);
        af[mt] = *(const bf16x8*)((const char*)As + rowa * 128 + sa * 16);
        int rowb = wn * 64 + mt * 16 + l15;
        int sb = (kk * 4 + lg) ^ (rowb & 7);
        bfr[mt] = *(const bf16x8*)((const char*)Bs + rowb * 128 + sb * 16);
      }
#pragma unroll
      for (int mt = 0; mt < 4; ++mt)
#pragma unroll
        for (int nt = 0; nt < 4; ++nt)
          acc[mt][nt] = __builtin_amdgcn_mfma_f32_16x16x32_bf16(
              af[mt], bfr[nt], acc[mt][nt], 0, 0, 0);
    }
  }

#pragma unroll
  for (int mt = 0; mt < 4; ++mt) {
#pragma unroll
    for (int nt = 0; nt < 4; ++nt) {
      int col = c0 + wn * 64 + nt * 16 + l15;
      float bv = bf2f(bias[col]);
      int rbase = r0 + wm * 64 + mt * 16 + lg * 4;
      if (OUTMODE == 1) {
        u16* out = (u16*)outv;
        int bb = rbase >> 11, t0 = rbase & (T_ - 1);
        int hh = col >> 6, dd = col & 63;
        u16x4 pk;
#pragma unroll
        for (int r = 0; r < 4; ++r) pk[r] = f2bf(acc[mt][nt][r] + bv);
        *(u16x4*)(out + (size_t)((bb * H_ + hh) * D_ + dd) * T_ + t0) = pk;
      } else if (OUTMODE == 0) {
        u16* out = (u16*)outv;
#pragma unroll
        for (int r = 0; r < 4; ++r) {
          int row = rbase + r;
          int bb = row >> 11, t = row & (T_ - 1);
          int hh = col >> 6, dd = col & 63;
          out[(size_t)((bb * H_ + hh) * T_ + t) * D_ + dd] =
              f2bf(acc[mt][nt][r] + bv);
        }
      } else {  // OUTMODE 2: float32 row-major
        float* out = (float*)outv;
#pragma unroll
        for (int r = 0; r < 4; ++r)
          out[(size_t)(rbase + r) * E_ + col] = acc[mt][nt][r] + bv;
      }
    }
  }
}

// ---------------- VALU flash attention (correctness anchor) -------
// One thread per q row. Q,K in (B,H,T,D); VT in (B,H,D,T). Output (B,T,E) bf16.
// phys_bias is constant over (q,k) per (b,h) => cancels in softmax.
__global__ __launch_bounds__(256, 2) void attn_valu_kernel(
    const u16* __restrict__ Q, const u16* __restrict__ K,
    const u16* __restrict__ VT, const float* __restrict__ mbg,
    u16* __restrict__ outb) {
  __shared__ __align__(16) float Ks[64][68];   // [key][d]
  __shared__ __align__(16) float Vs[64][68];   // [key][d]
  __shared__ __align__(16) float mbs[T_];
  const int bh = blockIdx.y, b = bh >> 4, h = bh & 15;
  const int tid = threadIdx.x;
  const int tq = blockIdx.x * 256 + tid;       // q row 0..2047

  for (int i = tid; i < T_; i += 256) mbs[i] = mbg[b * T_ + i];

  const u16* qrow = Q + ((size_t)bh * T_ + tq) * D_;
  f32x4 qv[16], ov[16];
#pragma unroll
  for (int c = 0; c < 8; ++c) {
    u16x8 v = *(const u16x8*)(qrow + c * 8);
    f32x4 lo = { bf2f(v[0]), bf2f(v[1]), bf2f(v[2]), bf2f(v[3]) };
    f32x4 hi = { bf2f(v[4]), bf2f(v[5]), bf2f(v[6]), bf2f(v[7]) };
    qv[c * 2] = lo; qv[c * 2 + 1] = hi;
  }
#pragma unroll
  for (int c = 0; c < 16; ++c) ov[c] = (f32x4){0.f, 0.f, 0.f, 0.f};

  float m = -30000.f, l = 0.f;
  const float cc = 0.125f * 1.44269504f;  // scale * log2(e)

  const u16* kb = K + (size_t)bh * T_ * D_;
  const u16* vb = VT + (size_t)bh * D_ * T_;

  for (int kt = 0; kt < 32; ++kt) {
    const int kk0 = kt * 64;
    __syncthreads();
    {  // stage K tile: thread -> (key = tid>>2, d-chunk of 16)
      int key = tid >> 2, c0 = (tid & 3) * 16;
      u16x8 a = *(const u16x8*)(kb + (size_t)(kk0 + key) * D_ + c0);
      u16x8 bb2 = *(const u16x8*)(kb + (size_t)(kk0 + key) * D_ + c0 + 8);
#pragma unroll
      for (int j = 0; j < 8; ++j) Ks[key][c0 + j] = bf2f(a[j]);
#pragma unroll
      for (int j = 0; j < 8; ++j) Ks[key][c0 + 8 + j] = bf2f(bb2[j]);
    }
    {  // stage V tile (transpose from VT): thread -> (d = tid>>2, key-chunk)
      int d = tid >> 2, kc = (tid & 3) * 16;
      u16x8 a = *(const u16x8*)(vb + (size_t)d * T_ + kk0 + kc);
      u16x8 bb2 = *(const u16x8*)(vb + (size_t)d * T_ + kk0 + kc + 8);
#pragma unroll
      for (int j = 0; j < 8; ++j) Vs[kc + j][d] = bf2f(a[j]);
#pragma unroll
      for (int j = 0; j < 8; ++j) Vs[kc + 8 + j][d] = bf2f(bb2[j]);
    }
    __syncthreads();

    for (int key = 0; key < 64; ++key) {
      const f32x4* krow = (const f32x4*)&Ks[key][0];
      f32x4 sv = {0.f, 0.f, 0.f, 0.f};
#pragma unroll
      for (int c = 0; c < 16; ++c) sv += qv[c] * krow[c];
      float s = sv[0] + sv[1] + sv[2] + sv[3];
      s += mbs[kk0 + key];              // additive mask in raw-score units
      if (s > m) {                      // online softmax rescale
        float f = exp2f((m - s) * cc);
        l *= f;
#pragma unroll
        for (int c = 0; c < 16; ++c) ov[c] *= f;
        m = s;
      }
      float p = exp2f((s - m) * cc);
      l += p;
      const f32x4* vrow = (const f32x4*)&Vs[key][0];
#pragma unroll
      for (int c = 0; c < 16; ++c) ov[c] += p * vrow[c];
    }
  }

  float invl = (l > 0.f) ? 1.f / l : 0.f;
  u16* orow = outb + (size_t)(b * T_ + tq) * E_ + h * D_;
#pragma unroll
  for (int c = 0; c < 8; ++c) {
    u16x8 v;
#pragma unroll
    for (int j = 0; j < 4; ++j) v[j] = f2bf(ov[c * 2][j] * invl);
#pragma unroll
    for (int j = 0; j < 4; ++j) v[4 + j] = f2bf(ov[c * 2 + 1][j] * invl);
    *(u16x8*)(orow + c * 8) = v;
  }
}

extern "C" void kernel_launch(void* const* d_in, const int* in_sizes, int n_in,
                              void* d_out, int out_size, void* d_ws, size_t ws_size,
                              hipStream_t stream) {
  const void* x    = d_in[0];
  // d_in[1] physics_state: UNUSED — per-(b,h) scalar bias cancels in softmax.
  const void* mask = d_in[2];
  const void* Wq = d_in[3];
  const void* bq = d_in[4];
  const void* Wk = d_in[5];
  const void* bk = d_in[6];
  const void* Wv = d_in[7];
  const void* bv = d_in[8];
  const void* Wo = d_in[9];
  const void* bo = d_in[10];
  char* ws = (char*)d_ws;

  // ---- workspace plan (<= 24.1 MB). d_out is 16 MB (4M f32) and doubles as
  // scratch: Qb bf16 in its lower 8 MB, xc bf16 in its upper 8 MB; both dead
  // before the final f32 GEMM overwrites d_out. ----
  const size_t MB = 1024 * 1024;
  u16* Kb   = (u16*)(ws + 0 * MB);          // 8 MB (B,H,T,D)
  u16* Vtb  = (u16*)(ws + 8 * MB);          // 8 MB (B,H,D,T)
  u16* Ab   = (u16*)(ws + 16 * MB);         // 8 MB attn out (B,T,E) bf16
  u16* WqT  = (u16*)(ws + 16 * MB);         // dead before attn writes Ab
  u16* WkT  = (u16*)(ws + 18 * MB);
  u16* WvT  = (u16*)(ws + 20 * MB);
  u16* Wc   = (u16*)(ws + 22 * MB);         // conv staging (2 MB)
  u16* WoT  = (u16*)(ws + 0 * MB);          // over Kb, written after attn
  u16* Wc2  = (u16*)(ws + 2 * MB);          // over Kb, after attn
  u16* bqc  = (u16*)(ws + 24 * MB + 0 * 4096);
  u16* bkc  = (u16*)(ws + 24 * MB + 1 * 4096);
  u16* bvc  = (u16*)(ws + 24 * MB + 2 * 4096);
  u16* boc  = (u16*)(ws + 24 * MB + 3 * 4096);
  float* mbg = (float*)(ws + 24 * MB + 16 * 1024);   // 16 KB
  int* flags = (int*)(ws + 24 * MB + 64 * 1024);

  u16* Qb = (u16*)d_out;                     // lower 8 MB of d_out
  u16* xc = (u16*)((char*)d_out + 8 * MB);   // upper 8 MB of d_out
  float* out = (float*)d_out;

  dim3 blk(256);
  const int NW = E_ * E_;          // 1M elems per weight
  const int NX = B_ * T_ * E_;     // 4M elems

  detect_kernel<<<1, blk, 0, stream>>>((const u16*)x, mask, flags);
  convf_kernel<<<NX / 8 / 256, blk, 0, stream>>>(x, xc, NX, flags);
  convf_kernel<<<1, blk, 0, stream>>>(bq, bqc, E_, flags);
  convf_kernel<<<1, blk, 0, stream>>>(bk, bkc, E_, flags);
  convf_kernel<<<1, blk, 0, stream>>>(bv, bvc, E_, flags);
  convf_kernel<<<1, blk, 0, stream>>>(bo, boc, E_, flags);
  maskbias_kernel<<<16, blk, 0, stream>>>(mask, mbg, flags);

  convf_kernel<<<NW / 8 / 256, blk, 0, stream>>>(Wq, Wc, NW, flags);
  wt_kernel<<<dim3(16, 16), blk, 0, stream>>>(Wc, WqT);
  convf_kernel<<<NW / 8 / 256, blk, 0, stream>>>(Wk, Wc, NW, flags);
  wt_kernel<<<dim3(16, 16), blk, 0, stream>>>(Wc, WkT);
  convf_kernel<<<NW / 8 / 256, blk, 0, stream>>>(Wv, Wc, NW, flags);
  wt_kernel<<<dim3(16, 16), blk, 0, stream>>>(Wc, WvT);

  gemm_kernel<0><<<dim3(32, 8), blk, 0, stream>>>(xc, WqT, bqc, Qb);
  gemm_kernel<0><<<dim3(32, 8), blk, 0, stream>>>(xc, WkT, bkc, Kb);
  gemm_kernel<1><<<dim3(32, 8), blk, 0, stream>>>(xc, WvT, bvc, Vtb);
  attn_valu_kernel<<<dim3(8, 32), blk, 0, stream>>>(Qb, Kb, Vtb, mbg, Ab);
  convf_kernel<<<NW / 8 / 256, blk, 0, stream>>>(Wo, Wc2, NW, flags);
  wt_kernel<<<dim3(16, 16), blk, 0, stream>>>(Wc2, WoT);
  gemm_kernel<2><<<dim3(32, 8), blk, 0, stream>>>(Ab, WoT, boc, out);
}

// Round 6
// 240.469 us; speedup vs baseline: 4.8841x; 4.8841x over previous
//
#include <hip/hip_runtime.h>
#include <hip/hip_bf16.h>
#include <stdint.h>

// Problem constants
#define E_  1024
#define H_  16
#define D_  64
#define T_  2048
#define B_  2

typedef unsigned short u16;
typedef unsigned char u8;
typedef __attribute__((ext_vector_type(8))) __bf16 bf16x8;
typedef __attribute__((ext_vector_type(4))) float f32x4;
typedef __attribute__((ext_vector_type(8))) u16 u16x8;
typedef __attribute__((ext_vector_type(4))) u16 u16x4;

__device__ __forceinline__ float bf2f(u16 u) {
  union { uint32_t u32; float f; } x; x.u32 = ((uint32_t)u) << 16; return x.f;
}
__device__ __forceinline__ u16 f2bf(float v) {
  union { float f; uint32_t u; } x; x.f = v;
  uint32_t r = x.u + 0x7fffu + ((x.u >> 16) & 1u);  // round-to-nearest-even
  return (u16)(r >> 16);
}
__device__ __forceinline__ void async16(const void* g, void* l) {
  __builtin_amdgcn_global_load_lds(
      (const __attribute__((address_space(1))) void*)g,
      (__attribute__((address_space(3))) void*)l, 16, 0, 0);
}

// ---------------- dtype detection ----------------
// flags[0]: 1 = float inputs are f32, 0 = bf16 (exponent-field statistics of
// even u16 halves). flags[1]: 1 = mask is int32, 0 = packed bytes.
__global__ __launch_bounds__(256) void detect_kernel(const u16* __restrict__ xu,
                                                     const void* __restrict__ mp,
                                                     int* __restrict__ flags) {
  __shared__ int cnt[2];
  const int tid = threadIdx.x;
  if (tid < 2) cnt[tid] = 0;
  __syncthreads();
  int c = 0;
  for (int i = tid; i < 4096; i += 256) {
    u16 u = xu[2 * i];
    int e = (u >> 7) & 0xFF;
    if (e != 0 && (e <= 0x40 || e >= 0xC0)) c++;
  }
  atomicAdd(&cnt[0], c);
  int m = 0;
  const unsigned int* mi = (const unsigned int*)mp;
  for (int i = tid; i < 1024; i += 256)
    if (mi[i] > 1u) m++;
  atomicAdd(&cnt[1], m);
  __syncthreads();
  if (tid == 0) {
    flags[0] = (cnt[0] > 409) ? 1 : 0;
    flags[1] = (cnt[1] == 0) ? 1 : 0;
  }
}

// canonicalize a float tensor (f32 or bf16 per flags[0]) to bf16
__global__ __launch_bounds__(256) void convf_kernel(const void* __restrict__ src,
                                                    u16* __restrict__ dst, int n,
                                                    const int* __restrict__ flags) {
  int i = (blockIdx.x * 256 + threadIdx.x) * 8;
  if (i >= n) return;
  if (flags[0]) {
    const float* s = (const float*)src;
    u16x8 o;
#pragma unroll
    for (int j = 0; j < 8; ++j) o[j] = f2bf(s[i + j]);
    *(u16x8*)(dst + i) = o;
  } else {
    *(u16x8*)(dst + i) = *(const u16x8*)((const u16*)src + i);
  }
}

// all four biases in one dispatch; dst slots spaced 2048 elems apart
__global__ __launch_bounds__(256) void bias4_kernel(
    const void* __restrict__ b0, const void* __restrict__ b1,
    const void* __restrict__ b2, const void* __restrict__ b3,
    u16* __restrict__ dst, const int* __restrict__ flags) {
  const void* src = (blockIdx.x == 0) ? b0 : (blockIdx.x == 1) ? b1
                    : (blockIdx.x == 2) ? b2 : b3;
  u16* d = dst + blockIdx.x * 2048;
  int t = threadIdx.x;
#pragma unroll
  for (int j = 0; j < 4; ++j) {
    int i = t + j * 256;
    d[i] = flags[0] ? f2bf(((const float*)src)[i]) : ((const u16*)src)[i];
  }
}

// mask -> additive bias table (0 keep, -1e5 drop), f32
__global__ __launch_bounds__(256) void maskbias_kernel(const void* __restrict__ mp,
                                                       float* __restrict__ mbg,
                                                       const int* __restrict__ flags) {
  int i = blockIdx.x * 256 + threadIdx.x;  // 4096 total
  int keep = flags[1] ? (((const int*)mp)[i] != 0) : (((const u8*)mp)[i] != 0);
  mbg[i] = keep ? 0.f : -1e5f;
}

// ------- fused weight convert(+f32->bf16) + transpose: WT[e][i] = W[i][e] ----
__global__ __launch_bounds__(256) void wtc_kernel(const void* __restrict__ Wv,
                                                  u16* __restrict__ WT,
                                                  const int* __restrict__ flags) {
  __shared__ __align__(16) u16 tile[64][65];
  const int bx = blockIdx.x * 64;   // source col block
  const int by = blockIdx.y * 64;   // source row block
  const int t = threadIdx.x;
  const int f32in = flags[0];
#pragma unroll
  for (int p = 0; p < 2; ++p) {
    int row = p * 32 + (t >> 3);
    int ch = t & 7;
    if (f32in) {
      const float* s = (const float*)Wv + (size_t)(by + row) * E_ + bx + ch * 8;
#pragma unroll
      for (int j = 0; j < 8; ++j) tile[row][ch * 8 + j] = f2bf(s[j]);
    } else {
      u16x8 v = *(const u16x8*)((const u16*)Wv + (size_t)(by + row) * E_ + bx + ch * 8);
#pragma unroll
      for (int j = 0; j < 8; ++j) tile[row][ch * 8 + j] = v[j];
    }
  }
  __syncthreads();
#pragma unroll
  for (int p = 0; p < 2; ++p) {
    int orow = p * 32 + (t >> 3);
    int ch = t & 7;
    u16x8 v;
#pragma unroll
    for (int j = 0; j < 8; ++j) v[j] = tile[ch * 8 + j][orow];
    *(u16x8*)(WT + (size_t)(bx + orow) * E_ + by + ch * 8) = v;
  }
}

// ---------------- GEMM: C[r][e] = sum_i A[r][i] * BT[e][i] + bias[e] --------
// OUTMODE 0: write (B,H,T,D) bf16   (Q, K)
// OUTMODE 1: write (B,H,D,T) bf16   (V transposed, packed 8B stores)
// OUTMODE 2: write row-major FLOAT32 (final output)
template <int OUTMODE>
__global__ __launch_bounds__(256, 2) void gemm_kernel(
    const u16* __restrict__ A, const u16* __restrict__ BTm,
    const u16* __restrict__ bias, void* __restrict__ outv) {
  __shared__ __align__(16) u16 As[128 * 64];
  __shared__ __align__(16) u16 Bs[128 * 64];
  const int tid = threadIdx.x, lane = tid & 63, wid = tid >> 6;
  const int wm = wid >> 1, wn = wid & 1;
  const int l15 = lane & 15, lg = lane >> 4;
  const int r0 = blockIdx.x * 128, c0 = blockIdx.y * 128;
  f32x4 acc[4][4] = {};

  for (int k0 = 0; k0 < E_; k0 += 64) {
    __syncthreads();
#pragma unroll
    for (int i = 0; i < 4; ++i) {
      int row = i * 32 + (tid >> 3);
      int g = (tid & 7) ^ (row & 7);  // inverse-swizzled global source (T2)
      async16(A + (size_t)(r0 + row) * E_ + k0 + g * 8,
              (char*)As + i * 4096 + tid * 16);
      async16(BTm + (size_t)(c0 + row) * E_ + k0 + g * 8,
              (char*)Bs + i * 4096 + tid * 16);
    }
    __syncthreads();
#pragma unroll
    for (int kk = 0; kk < 2; ++kk) {
      bf16x8 af[4], bfr[4];
#pragma unroll
      for (int mt = 0; mt < 4; ++mt) {
        int rowa = wm * 64 + mt * 16 + l15;
        int sa = (kk * 4 + lg) ^ (rowa & 7);
        af[mt] = *(const bf16x8*)((const char*)As + rowa * 128 + sa * 16);
        int rowb = wn * 64 + mt * 16 + l15;
        int sb = (kk * 4 + lg) ^ (rowb & 7);
        bfr[mt] = *(const bf16x8*)((const char*)Bs + rowb * 128 + sb * 16);
      }
#pragma unroll
      for (int mt = 0; mt < 4; ++mt)
#pragma unroll
        for (int nt = 0; nt < 4; ++nt)
          acc[mt][nt] = __builtin_amdgcn_mfma_f32_16x16x32_bf16(
              af[mt], bfr[nt], acc[mt][nt], 0, 0, 0);
    }
  }

#pragma unroll
  for (int mt = 0; mt < 4; ++mt) {
#pragma unroll
    for (int nt = 0; nt < 4; ++nt) {
      int col = c0 + wn * 64 + nt * 16 + l15;
      float bv = bf2f(bias[col]);
      int rbase = r0 + wm * 64 + mt * 16 + lg * 4;
      if (OUTMODE == 1) {
        u16* out = (u16*)outv;
        int bb = rbase >> 11, t0 = rbase & (T_ - 1);
        int hh = col >> 6, dd = col & 63;
        u16x4 pk;
#pragma unroll
        for (int r = 0; r < 4; ++r) pk[r] = f2bf(acc[mt][nt][r] + bv);
        *(u16x4*)(out + (size_t)((bb * H_ + hh) * D_ + dd) * T_ + t0) = pk;
      } else if (OUTMODE == 0) {
        u16* out = (u16*)outv;
#pragma unroll
        for (int r = 0; r < 4; ++r) {
          int row = rbase + r;
          int bb = row >> 11, t = row & (T_ - 1);
          int hh = col >> 6, dd = col & 63;
          out[(size_t)((bb * H_ + hh) * T_ + t) * D_ + dd] =
              f2bf(acc[mt][nt][r] + bv);
        }
      } else {  // OUTMODE 2: float32 row-major
        float* out = (float*)outv;
#pragma unroll
        for (int r = 0; r < 4; ++r)
          out[(size_t)(rbase + r) * E_ + col] = acc[mt][nt][r] + bv;
      }
    }
  }
}

// ---------------- MFMA flash attention ----------------
// phys_bias is constant over (q,k) per (b,h) => cancels in softmax.
// grid (T/128, B*H), 256 threads = 4 waves, each wave owns 32 q-rows.
__global__ __launch_bounds__(256, 2) void attn_kernel(
    const u16* __restrict__ Q, const u16* __restrict__ K,
    const u16* __restrict__ VT, const float* __restrict__ mbg,
    u16* __restrict__ outb) {
  __shared__ __align__(16) u16 Ks[128 * 64];    // K tile [key][d], swizzled
  __shared__ __align__(16) u16 Vs[64 * 128];    // V^T tile [d][key], swizzled
  __shared__ __align__(16) u16 Ps[4][32 * 136]; // per-wave P, +8 pad
  __shared__ __align__(16) float mb[T_];        // additive mask bias
  const int bh = blockIdx.y, b = bh >> 4, h = bh & 15;
  const int q0 = blockIdx.x * 128;
  const int tid = threadIdx.x, lane = tid & 63, w = tid >> 6;
  const int l15 = lane & 15, lg = lane >> 4;

  for (int i = tid; i < T_; i += 256) mb[i] = mbg[b * T_ + i];

  const u16* qb = Q + (size_t)bh * T_ * D_;
  const u16* kb = K + (size_t)bh * T_ * D_;
  const u16* vb = VT + (size_t)bh * D_ * T_;

  bf16x8 qf[2][2];  // Q hoisted to registers: A-frag row=l15, k=kd*32+lg*8
#pragma unroll
  for (int mt = 0; mt < 2; ++mt)
#pragma unroll
    for (int kd = 0; kd < 2; ++kd) {
      int row = q0 + w * 32 + mt * 16 + l15;
      qf[mt][kd] = *(const bf16x8*)(qb + (size_t)row * D_ + kd * 32 + lg * 8);
    }

  f32x4 o[2][4] = {};
  float mrow[2][4], lrow[2][4];
#pragma unroll
  for (int mt = 0; mt < 2; ++mt)
#pragma unroll
    for (int r = 0; r < 4; ++r) { mrow[mt][r] = 0.f; lrow[mt][r] = 0.f; }

  const float cc = 0.125f * 1.44269504f;  // scale * log2(e)

  for (int kt = 0; kt < 16; ++kt) {
    const int kk0 = kt * 128;
    __syncthreads();
#pragma unroll
    for (int i = 0; i < 4; ++i) {   // K tile: 128 keys x 64 d
      int row = i * 32 + (tid >> 3);
      int g = (tid & 7) ^ (row & 7);
      async16(kb + (size_t)(kk0 + row) * D_ + g * 8,
              (char*)Ks + i * 4096 + tid * 16);
    }
#pragma unroll
    for (int i = 0; i < 4; ++i) {   // V^T tile: 64 d x 128 keys
      int row = i * 16 + (tid >> 4);
      int g = (tid & 15) ^ (row & 7);
      async16(vb + (size_t)row * T_ + kk0 + g * 8,
              (char*)Vs + i * 4096 + tid * 16);
    }
    __syncthreads();

    // S = Q K^T  (32 q x 128 k per wave)
    f32x4 s[2][8] = {};
#pragma unroll
    for (int kd = 0; kd < 2; ++kd) {
      bf16x8 kf[8];
#pragma unroll
      for (int nf = 0; nf < 8; ++nf) {
        int row = nf * 16 + l15;
        int slot = (kd * 4 + lg) ^ (row & 7);
        kf[nf] = *(const bf16x8*)((const char*)Ks + row * 128 + slot * 16);
      }
#pragma unroll
      for (int mt = 0; mt < 2; ++mt)
#pragma unroll
        for (int nf = 0; nf < 8; ++nf)
          s[mt][nf] = __builtin_amdgcn_mfma_f32_16x16x32_bf16(
              qf[mt][kd], kf[nf], s[mt][nf], 0, 0, 0);
    }

    // additive key mask
    float mbv[8];
#pragma unroll
    for (int nf = 0; nf < 8; ++nf) mbv[nf] = mb[kk0 + nf * 16 + l15];
#pragma unroll
    for (int mt = 0; mt < 2; ++mt)
#pragma unroll
      for (int nf = 0; nf < 8; ++nf)
#pragma unroll
        for (int r = 0; r < 4; ++r) s[mt][nf][r] += mbv[nf];

    // online softmax: running max (init 0 — safe, scores O(1)) + rescale
#pragma unroll
    for (int mt = 0; mt < 2; ++mt) {
#pragma unroll
      for (int r = 0; r < 4; ++r) {
        float tm = s[mt][0][r];
#pragma unroll
        for (int nf = 1; nf < 8; ++nf) tm = fmaxf(tm, s[mt][nf][r]);
        tm = fmaxf(tm, __shfl_xor(tm, 1));
        tm = fmaxf(tm, __shfl_xor(tm, 2));
        tm = fmaxf(tm, __shfl_xor(tm, 4));
        tm = fmaxf(tm, __shfl_xor(tm, 8));
        float nm = fmaxf(mrow[mt][r], tm);
        float f = exp2f((mrow[mt][r] - nm) * cc);
        mrow[mt][r] = nm;
        lrow[mt][r] *= f;
#pragma unroll
        for (int df = 0; df < 4; ++df) o[mt][df][r] *= f;
      }
    }

    // P = exp2((s - m)*cc), accumulate row sums, stage P into LDS
#pragma unroll
    for (int mt = 0; mt < 2; ++mt) {
      float rs[4] = {0.f, 0.f, 0.f, 0.f};
#pragma unroll
      for (int nf = 0; nf < 8; ++nf) {
#pragma unroll
        for (int r = 0; r < 4; ++r) {
          float p = exp2f((s[mt][nf][r] - mrow[mt][r]) * cc);
          rs[r] += p;
          int prow = mt * 16 + lg * 4 + r;
          Ps[w][prow * 136 + nf * 16 + l15] = f2bf(p);
        }
      }
#pragma unroll
      for (int r = 0; r < 4; ++r) {
        float t = rs[r];
        t += __shfl_xor(t, 1);
        t += __shfl_xor(t, 2);
        t += __shfl_xor(t, 4);
        t += __shfl_xor(t, 8);
        lrow[mt][r] += t;
      }
    }

    asm volatile("s_waitcnt lgkmcnt(0)" ::: "memory");  // P writes -> reads

    // O += P V  (k in 4 chunks of 32)
#pragma unroll
    for (int kk = 0; kk < 4; ++kk) {
      bf16x8 pf[2], vf[4];
#pragma unroll
      for (int mt = 0; mt < 2; ++mt)
        pf[mt] = *(const bf16x8*)((const char*)&Ps[w][0] +
                                  (mt * 16 + l15) * 272 + kk * 64 + lg * 16);
#pragma unroll
      for (int df = 0; df < 4; ++df) {
        int row = df * 16 + l15;
        int slot = (kk * 4 + lg) ^ (row & 7);
        vf[df] = *(const bf16x8*)((const char*)Vs + row * 256 + slot * 16);
      }
#pragma unroll
      for (int mt = 0; mt < 2; ++mt)
#pragma unroll
        for (int df = 0; df < 4; ++df)
          o[mt][df] = __builtin_amdgcn_mfma_f32_16x16x32_bf16(
              pf[mt], vf[df], o[mt][df], 0, 0, 0);
    }
  }

  // epilogue -> attn buffer (B,T,E) row-major bf16
  float inv[2][4];
#pragma unroll
  for (int mt = 0; mt < 2; ++mt)
#pragma unroll
    for (int r = 0; r < 4; ++r)
      inv[mt][r] = (lrow[mt][r] > 0.f) ? 1.0f / lrow[mt][r] : 0.f;
#pragma unroll
  for (int mt = 0; mt < 2; ++mt)
#pragma unroll
    for (int df = 0; df < 4; ++df)
#pragma unroll
      for (int r = 0; r < 4; ++r) {
        int row = q0 + w * 32 + mt * 16 + lg * 4 + r;
        int col = h * D_ + df * 16 + l15;
        outb[(size_t)(b * T_ + row) * E_ + col] = f2bf(o[mt][df][r] * inv[mt][r]);
      }
}

extern "C" void kernel_launch(void* const* d_in, const int* in_sizes, int n_in,
                              void* d_out, int out_size, void* d_ws, size_t ws_size,
                              hipStream_t stream) {
  const void* x    = d_in[0];
  // d_in[1] physics_state: UNUSED — per-(b,h) scalar bias cancels in softmax.
  const void* mask = d_in[2];
  const void* Wq = d_in[3];
  const void* bq = d_in[4];
  const void* Wk = d_in[5];
  const void* bk = d_in[6];
  const void* Wv = d_in[7];
  const void* bv = d_in[8];
  const void* Wo = d_in[9];
  const void* bo = d_in[10];
  char* ws = (char*)d_ws;

  // ---- workspace plan (<= 24.1 MB). d_out is 16 MB (4M f32) and doubles as
  // scratch: Qb bf16 in lower 8 MB, xc bf16 in upper 8 MB; both dead before
  // the final f32 GEMM overwrites d_out. ----
  const size_t MB = 1024 * 1024;
  u16* Kb   = (u16*)(ws + 0 * MB);          // 8 MB (B,H,T,D)
  u16* Vtb  = (u16*)(ws + 8 * MB);          // 8 MB (B,H,D,T)
  u16* Ab   = (u16*)(ws + 16 * MB);         // 8 MB attn out (B,T,E) bf16
  u16* WqT  = (u16*)(ws + 16 * MB);         // dead before attn writes Ab
  u16* WkT  = (u16*)(ws + 18 * MB);
  u16* WvT  = (u16*)(ws + 20 * MB);
  u16* WoT  = (u16*)(ws + 0 * MB);          // over Kb, written after attn
  u16* bqc  = (u16*)(ws + 24 * MB + 0 * 4096);
  u16* bkc  = (u16*)(ws + 24 * MB + 1 * 4096);
  u16* bvc  = (u16*)(ws + 24 * MB + 2 * 4096);
  u16* boc  = (u16*)(ws + 24 * MB + 3 * 4096);
  float* mbg = (float*)(ws + 24 * MB + 16 * 1024);   // 16 KB
  int* flags = (int*)(ws + 24 * MB + 64 * 1024);

  u16* Qb = (u16*)d_out;                     // lower 8 MB of d_out
  u16* xc = (u16*)((char*)d_out + 8 * MB);   // upper 8 MB of d_out
  float* out = (float*)d_out;

  dim3 blk(256);
  const int NX = B_ * T_ * E_;     // 4M elems

  detect_kernel<<<1, blk, 0, stream>>>((const u16*)x, mask, flags);
  convf_kernel<<<NX / 8 / 256, blk, 0, stream>>>(x, xc, NX, flags);
  bias4_kernel<<<4, blk, 0, stream>>>(bq, bk, bv, bo, bqc, flags);
  maskbias_kernel<<<16, blk, 0, stream>>>(mask, mbg, flags);

  wtc_kernel<<<dim3(16, 16), blk, 0, stream>>>(Wq, WqT, flags);
  wtc_kernel<<<dim3(16, 16), blk, 0, stream>>>(Wk, WkT, flags);
  wtc_kernel<<<dim3(16, 16), blk, 0, stream>>>(Wv, WvT, flags);

  gemm_kernel<0><<<dim3(32, 8), blk, 0, stream>>>(xc, WqT, bqc, Qb);
  gemm_kernel<0><<<dim3(32, 8), blk, 0, stream>>>(xc, WkT, bkc, Kb);
  gemm_kernel<1><<<dim3(32, 8), blk, 0, stream>>>(xc, WvT, bvc, Vtb);
  attn_kernel<<<dim3(16, 32), blk, 0, stream>>>(Qb, Kb, Vtb, mbg, Ab);
  wtc_kernel<<<dim3(16, 16), blk, 0, stream>>>(Wo, WoT, flags);  // Kb dead now
  gemm_kernel<2><<<dim3(32, 8), blk, 0, stream>>>(Ab, WoT, boc, out);
}

// Round 7
// 154.984 us; speedup vs baseline: 7.5781x; 1.5516x over previous
//
#include <hip/hip_runtime.h>
#include <hip/hip_bf16.h>
#include <stdint.h>

// Problem constants
#define E_  1024
#define H_  16
#define D_  64
#define T_  2048
#define B_  2

typedef unsigned short u16;
typedef unsigned char u8;
typedef __attribute__((ext_vector_type(8))) __bf16 bf16x8;
typedef __attribute__((ext_vector_type(4))) float f32x4;
typedef __attribute__((ext_vector_type(8))) u16 u16x8;
typedef __attribute__((ext_vector_type(4))) u16 u16x4;

__device__ __forceinline__ float bf2f(u16 u) {
  union { uint32_t u32; float f; } x; x.u32 = ((uint32_t)u) << 16; return x.f;
}
__device__ __forceinline__ u16 f2bf(float v) {
  union { float f; uint32_t u; } x; x.f = v;
  uint32_t r = x.u + 0x7fffu + ((x.u >> 16) & 1u);  // round-to-nearest-even
  return (u16)(r >> 16);
}
__device__ __forceinline__ void async16(const void* g, void* l) {
  __builtin_amdgcn_global_load_lds(
      (const __attribute__((address_space(1))) void*)g,
      (__attribute__((address_space(3))) void*)l, 16, 0, 0);
}

// ---------------- dtype detection ----------------
__global__ __launch_bounds__(256) void detect_kernel(const u16* __restrict__ xu,
                                                     const void* __restrict__ mp,
                                                     int* __restrict__ flags) {
  __shared__ int cnt[2];
  const int tid = threadIdx.x;
  if (tid < 2) cnt[tid] = 0;
  __syncthreads();
  int c = 0;
  for (int i = tid; i < 4096; i += 256) {
    u16 u = xu[2 * i];
    int e = (u >> 7) & 0xFF;
    if (e != 0 && (e <= 0x40 || e >= 0xC0)) c++;
  }
  atomicAdd(&cnt[0], c);
  int m = 0;
  const unsigned int* mi = (const unsigned int*)mp;
  for (int i = tid; i < 1024; i += 256)
    if (mi[i] > 1u) m++;
  atomicAdd(&cnt[1], m);
  __syncthreads();
  if (tid == 0) {
    flags[0] = (cnt[0] > 409) ? 1 : 0;
    flags[1] = (cnt[1] == 0) ? 1 : 0;
  }
}

// canonicalize a float tensor (f32 or bf16 per flags[0]) to bf16
__global__ __launch_bounds__(256) void convf_kernel(const void* __restrict__ src,
                                                    u16* __restrict__ dst, int n,
                                                    const int* __restrict__ flags) {
  int i = (blockIdx.x * 256 + threadIdx.x) * 8;
  if (i >= n) return;
  if (flags[0]) {
    const float* s = (const float*)src;
    u16x8 o;
#pragma unroll
    for (int j = 0; j < 8; ++j) o[j] = f2bf(s[i + j]);
    *(u16x8*)(dst + i) = o;
  } else {
    *(u16x8*)(dst + i) = *(const u16x8*)((const u16*)src + i);
  }
}

// all four biases in one dispatch; dst slots spaced 2048 elems apart
__global__ __launch_bounds__(256) void bias4_kernel(
    const void* __restrict__ b0, const void* __restrict__ b1,
    const void* __restrict__ b2, const void* __restrict__ b3,
    u16* __restrict__ dst, const int* __restrict__ flags) {
  const void* src = (blockIdx.x == 0) ? b0 : (blockIdx.x == 1) ? b1
                    : (blockIdx.x == 2) ? b2 : b3;
  u16* d = dst + blockIdx.x * 2048;
  int t = threadIdx.x;
#pragma unroll
  for (int j = 0; j < 4; ++j) {
    int i = t + j * 256;
    d[i] = flags[0] ? f2bf(((const float*)src)[i]) : ((const u16*)src)[i];
  }
}

// mask -> additive bias table (0 keep, -1e5 drop), f32
__global__ __launch_bounds__(256) void maskbias_kernel(const void* __restrict__ mp,
                                                       float* __restrict__ mbg,
                                                       const int* __restrict__ flags) {
  int i = blockIdx.x * 256 + threadIdx.x;  // 4096 total
  int keep = flags[1] ? (((const int*)mp)[i] != 0) : (((const u8*)mp)[i] != 0);
  mbg[i] = keep ? 0.f : -1e5f;
}

// ------- fused weight convert(+f32->bf16) + transpose: WT[e][i] = W[i][e] ----
__global__ __launch_bounds__(256) void wtc_kernel(const void* __restrict__ Wv,
                                                  u16* __restrict__ WT,
                                                  const int* __restrict__ flags) {
  __shared__ __align__(16) u16 tile[64][65];
  const int bx = blockIdx.x * 64;   // source col block
  const int by = blockIdx.y * 64;   // source row block
  const int t = threadIdx.x;
  const int f32in = flags[0];
#pragma unroll
  for (int p = 0; p < 2; ++p) {
    int row = p * 32 + (t >> 3);
    int ch = t & 7;
    if (f32in) {
      const float* s = (const float*)Wv + (size_t)(by + row) * E_ + bx + ch * 8;
#pragma unroll
      for (int j = 0; j < 8; ++j) tile[row][ch * 8 + j] = f2bf(s[j]);
    } else {
      u16x8 v = *(const u16x8*)((const u16*)Wv + (size_t)(by + row) * E_ + bx + ch * 8);
#pragma unroll
      for (int j = 0; j < 8; ++j) tile[row][ch * 8 + j] = v[j];
    }
  }
  __syncthreads();
#pragma unroll
  for (int p = 0; p < 2; ++p) {
    int orow = p * 32 + (t >> 3);
    int ch = t & 7;
    u16x8 v;
#pragma unroll
    for (int j = 0; j < 8; ++j) v[j] = tile[ch * 8 + j][orow];
    *(u16x8*)(WT + (size_t)(bx + orow) * E_ + by + ch * 8) = v;
  }
}

// ---------------- fused QKV GEMM -------------------------------------------
// A: 4096x1024 bf16. BTm: 3072x1024 (WqT|WkT|WvT contiguous).
// cols 0..1023 -> Q (B,H,T,D); 1024..2047 -> K (B,H,T,D); 2048..3071 -> V^T.
__global__ __launch_bounds__(256, 2) void gemm_qkv_kernel(
    const u16* __restrict__ A, const u16* __restrict__ BTm,
    const u16* __restrict__ biases, u16* __restrict__ Qb,
    u16* __restrict__ Kb, u16* __restrict__ Vtb) {
  __shared__ __align__(16) u16 As[128 * 64];
  __shared__ __align__(16) u16 Bs[128 * 64];
  const int tid = threadIdx.x, lane = tid & 63, wid = tid >> 6;
  const int wm = wid >> 1, wn = wid & 1;
  const int l15 = lane & 15, lg = lane >> 4;
  const int r0 = blockIdx.x * 128, c0 = blockIdx.y * 128;
  f32x4 acc[4][4] = {};

  for (int k0 = 0; k0 < E_; k0 += 64) {
    __syncthreads();
#pragma unroll
    for (int i = 0; i < 4; ++i) {
      int row = i * 32 + (tid >> 3);
      int g = (tid & 7) ^ (row & 7);  // inverse-swizzled global source (T2)
      async16(A + (size_t)(r0 + row) * E_ + k0 + g * 8,
              (char*)As + i * 4096 + tid * 16);
      async16(BTm + (size_t)(c0 + row) * E_ + k0 + g * 8,
              (char*)Bs + i * 4096 + tid * 16);
    }
    __syncthreads();
#pragma unroll
    for (int kk = 0; kk < 2; ++kk) {
      bf16x8 af[4], bfr[4];
#pragma unroll
      for (int mt = 0; mt < 4; ++mt) {
        int rowa = wm * 64 + mt * 16 + l15;
        int sa = (kk * 4 + lg) ^ (rowa & 7);
        af[mt] = *(const bf16x8*)((const char*)As + rowa * 128 + sa * 16);
        int rowb = wn * 64 + mt * 16 + l15;
        int sb = (kk * 4 + lg) ^ (rowb & 7);
        bfr[mt] = *(const bf16x8*)((const char*)Bs + rowb * 128 + sb * 16);
      }
#pragma unroll
      for (int mt = 0; mt < 4; ++mt)
#pragma unroll
        for (int nt = 0; nt < 4; ++nt)
          acc[mt][nt] = __builtin_amdgcn_mfma_f32_16x16x32_bf16(
              af[mt], bfr[nt], acc[mt][nt], 0, 0, 0);
    }
  }

  const int sel = c0 >> 10;           // 0=Q, 1=K, 2=V
  u16* outp = (sel == 0) ? Qb : Kb;   // sel 2 handled separately
#pragma unroll
  for (int mt = 0; mt < 4; ++mt) {
#pragma unroll
    for (int nt = 0; nt < 4; ++nt) {
      int colG = c0 + wn * 64 + nt * 16 + l15;
      int colL = colG & 1023;
      float bv = bf2f(biases[sel * 2048 + colL]);
      int rbase = r0 + wm * 64 + mt * 16 + lg * 4;
      int hh = colL >> 6, dd = colL & 63;
      if (sel == 2) {  // V transposed (B,H,D,T), packed 8B stores
        int bb = rbase >> 11, t0 = rbase & (T_ - 1);
        u16x4 pk;
#pragma unroll
        for (int r = 0; r < 4; ++r) pk[r] = f2bf(acc[mt][nt][r] + bv);
        *(u16x4*)(Vtb + (size_t)((bb * H_ + hh) * D_ + dd) * T_ + t0) = pk;
      } else {         // Q/K (B,H,T,D)
#pragma unroll
        for (int r = 0; r < 4; ++r) {
          int row = rbase + r;
          int bb = row >> 11, t = row & (T_ - 1);
          outp[(size_t)((bb * H_ + hh) * T_ + t) * D_ + dd] =
              f2bf(acc[mt][nt][r] + bv);
        }
      }
    }
  }
}

// ---------------- final GEMM: C[r][e] = sum_i A[r][i]*BT[e][i] + bias, f32 --
__global__ __launch_bounds__(256, 2) void gemm_out_kernel(
    const u16* __restrict__ A, const u16* __restrict__ BTm,
    const u16* __restrict__ bias, float* __restrict__ out) {
  __shared__ __align__(16) u16 As[128 * 64];
  __shared__ __align__(16) u16 Bs[128 * 64];
  const int tid = threadIdx.x, lane = tid & 63, wid = tid >> 6;
  const int wm = wid >> 1, wn = wid & 1;
  const int l15 = lane & 15, lg = lane >> 4;
  const int r0 = blockIdx.x * 128, c0 = blockIdx.y * 128;
  f32x4 acc[4][4] = {};

  for (int k0 = 0; k0 < E_; k0 += 64) {
    __syncthreads();
#pragma unroll
    for (int i = 0; i < 4; ++i) {
      int row = i * 32 + (tid >> 3);
      int g = (tid & 7) ^ (row & 7);
      async16(A + (size_t)(r0 + row) * E_ + k0 + g * 8,
              (char*)As + i * 4096 + tid * 16);
      async16(BTm + (size_t)(c0 + row) * E_ + k0 + g * 8,
              (char*)Bs + i * 4096 + tid * 16);
    }
    __syncthreads();
#pragma unroll
    for (int kk = 0; kk < 2; ++kk) {
      bf16x8 af[4], bfr[4];
#pragma unroll
      for (int mt = 0; mt < 4; ++mt) {
        int rowa = wm * 64 + mt * 16 + l15;
        int sa = (kk * 4 + lg) ^ (rowa & 7);
        af[mt] = *(const bf16x8*)((const char*)As + rowa * 128 + sa * 16);
        int rowb = wn * 64 + mt * 16 + l15;
        int sb = (kk * 4 + lg) ^ (rowb & 7);
        bfr[mt] = *(const bf16x8*)((const char*)Bs + rowb * 128 + sb * 16);
      }
#pragma unroll
      for (int mt = 0; mt < 4; ++mt)
#pragma unroll
        for (int nt = 0; nt < 4; ++nt)
          acc[mt][nt] = __builtin_amdgcn_mfma_f32_16x16x32_bf16(
              af[mt], bfr[nt], acc[mt][nt], 0, 0, 0);
    }
  }

#pragma unroll
  for (int mt = 0; mt < 4; ++mt)
#pragma unroll
    for (int nt = 0; nt < 4; ++nt) {
      int col = c0 + wn * 64 + nt * 16 + l15;
      float bv = bf2f(bias[col]);
      int rbase = r0 + wm * 64 + mt * 16 + lg * 4;
#pragma unroll
      for (int r = 0; r < 4; ++r)
        out[(size_t)(rbase + r) * E_ + col] = acc[mt][nt][r] + bv;
    }
}

// ---------------- MFMA flash attention ----------------
// phys_bias cancels in softmax. Fixed-shift softmax (no online max): scores
// are statistically bounded (|s_scaled| <~ 2), shift SH=4 scaled keeps
// p in [e^-7, e^-2] — safe in bf16/f32. 1D grid 512, XCD-local bh decode.
__global__ __launch_bounds__(256, 2) void attn_kernel(
    const u16* __restrict__ Q, const u16* __restrict__ K,
    const u16* __restrict__ VT, const float* __restrict__ mbg,
    u16* __restrict__ outb) {
  __shared__ __align__(16) u16 Ks[128 * 64];    // K tile [key][d], swizzled
  __shared__ __align__(16) u16 Vs[64 * 128];    // V^T tile [d][key], swizzled
  __shared__ __align__(16) u16 Ps[4][32 * 136]; // per-wave P, +8 pad
  __shared__ __align__(16) float mb[T_];        // additive mask bias
  // XCD-local decode: all 16 q-blocks of a head land on one XCD (L2 reuse)
  const int wg = blockIdx.x;
  const int xcd = wg & 7, slot = wg >> 3;
  const int bh = xcd + 8 * (slot >> 4);
  const int q0 = (slot & 15) * 128;
  const int b = bh >> 4, h = bh & 15;
  const int tid = threadIdx.x, lane = tid & 63, w = tid >> 6;
  const int l15 = lane & 15, lg = lane >> 4;

  for (int i = tid; i < T_; i += 256) mb[i] = mbg[b * T_ + i];

  const u16* qb = Q + (size_t)bh * T_ * D_;
  const u16* kb = K + (size_t)bh * T_ * D_;
  const u16* vb = VT + (size_t)bh * D_ * T_;

  bf16x8 qf[2][2];  // Q hoisted: A-frag row=l15, k=kd*32+lg*8
#pragma unroll
  for (int mt = 0; mt < 2; ++mt)
#pragma unroll
    for (int kd = 0; kd < 2; ++kd) {
      int row = q0 + w * 32 + mt * 16 + l15;
      qf[mt][kd] = *(const bf16x8*)(qb + (size_t)row * D_ + kd * 32 + lg * 8);
    }

  f32x4 o[2][4] = {};
  float lrow[2][4];
#pragma unroll
  for (int mt = 0; mt < 2; ++mt)
#pragma unroll
    for (int r = 0; r < 4; ++r) lrow[mt][r] = 0.f;

  const float cc = 0.125f * 1.44269504f;  // scale * log2(e)
  const float SH = 4.0f * 1.44269504f;    // fixed shift (4 in scaled units)

  for (int kt = 0; kt < 16; ++kt) {
    const int kk0 = kt * 128;
    __syncthreads();
#pragma unroll
    for (int i = 0; i < 4; ++i) {   // K tile: 128 keys x 64 d
      int row = i * 32 + (tid >> 3);
      int g = (tid & 7) ^ (row & 7);
      async16(kb + (size_t)(kk0 + row) * D_ + g * 8,
              (char*)Ks + i * 4096 + tid * 16);
    }
#pragma unroll
    for (int i = 0; i < 4; ++i) {   // V^T tile: 64 d x 128 keys
      int row = i * 16 + (tid >> 4);
      int g = (tid & 15) ^ (row & 7);
      async16(vb + (size_t)row * T_ + kk0 + g * 8,
              (char*)Vs + i * 4096 + tid * 16);
    }
    __syncthreads();

    // S = Q K^T  (32 q x 128 k per wave)
    f32x4 s[2][8] = {};
#pragma unroll
    for (int kd = 0; kd < 2; ++kd) {
      bf16x8 kf[8];
#pragma unroll
      for (int nf = 0; nf < 8; ++nf) {
        int row = nf * 16 + l15;
        int slot2 = (kd * 4 + lg) ^ (row & 7);
        kf[nf] = *(const bf16x8*)((const char*)Ks + row * 128 + slot2 * 16);
      }
      __builtin_amdgcn_s_setprio(1);
#pragma unroll
      for (int mt = 0; mt < 2; ++mt)
#pragma unroll
        for (int nf = 0; nf < 8; ++nf)
          s[mt][nf] = __builtin_amdgcn_mfma_f32_16x16x32_bf16(
              qf[mt][kd], kf[nf], s[mt][nf], 0, 0, 0);
      __builtin_amdgcn_s_setprio(0);
    }

    // additive key mask
    float mbv[8];
#pragma unroll
    for (int nf = 0; nf < 8; ++nf) mbv[nf] = mb[kk0 + nf * 16 + l15];

    // P = exp2(s*cc - SH), accumulate per-lane row partial sums, stage P
#pragma unroll
    for (int mt = 0; mt < 2; ++mt) {
#pragma unroll
      for (int nf = 0; nf < 8; ++nf) {
#pragma unroll
        for (int r = 0; r < 4; ++r) {
          float p = exp2f(fmaf(s[mt][nf][r] + mbv[nf], cc, -SH));
          lrow[mt][r] += p;
          int prow = mt * 16 + lg * 4 + r;
          Ps[w][prow * 136 + nf * 16 + l15] = f2bf(p);
        }
      }
    }

    asm volatile("s_waitcnt lgkmcnt(0)" ::: "memory");  // P writes -> reads
    __builtin_amdgcn_sched_barrier(0);

    // O += P V  (k in 4 chunks of 32)
#pragma unroll
    for (int kk = 0; kk < 4; ++kk) {
      bf16x8 pf[2], vf[4];
#pragma unroll
      for (int mt = 0; mt < 2; ++mt)
        pf[mt] = *(const bf16x8*)((const char*)&Ps[w][0] +
                                  (mt * 16 + l15) * 272 + kk * 64 + lg * 16);
#pragma unroll
      for (int df = 0; df < 4; ++df) {
        int row = df * 16 + l15;
        int slot2 = (kk * 4 + lg) ^ (row & 7);
        vf[df] = *(const bf16x8*)((const char*)Vs + row * 256 + slot2 * 16);
      }
      __builtin_amdgcn_s_setprio(1);
#pragma unroll
      for (int mt = 0; mt < 2; ++mt)
#pragma unroll
        for (int df = 0; df < 4; ++df)
          o[mt][df] = __builtin_amdgcn_mfma_f32_16x16x32_bf16(
              pf[mt], vf[df], o[mt][df], 0, 0, 0);
      __builtin_amdgcn_s_setprio(0);
    }
  }

  // final l-reduction across the 16 l15 lanes (cols), once
  float inv[2][4];
#pragma unroll
  for (int mt = 0; mt < 2; ++mt)
#pragma unroll
    for (int r = 0; r < 4; ++r) {
      float t = lrow[mt][r];
      t += __shfl_xor(t, 1);
      t += __shfl_xor(t, 2);
      t += __shfl_xor(t, 4);
      t += __shfl_xor(t, 8);
      inv[mt][r] = (t > 0.f) ? 1.0f / t : 0.f;
    }

  // stage o/l into Ps[w] (per-wave private), then vector-store 16B chunks
#pragma unroll
  for (int mt = 0; mt < 2; ++mt)
#pragma unroll
    for (int df = 0; df < 4; ++df)
#pragma unroll
      for (int r = 0; r < 4; ++r) {
        int prow = mt * 16 + lg * 4 + r;
        Ps[w][prow * 136 + df * 16 + l15] = f2bf(o[mt][df][r] * inv[mt][r]);
      }
  asm volatile("s_waitcnt lgkmcnt(0)" ::: "memory");
  __builtin_amdgcn_sched_barrier(0);
  {
    int rowL = lane >> 1;            // 0..31
    int c8 = lane & 1;               // chunk parity
    int grow = b * T_ + q0 + w * 32 + rowL;
#pragma unroll
    for (int j = 0; j < 4; ++j) {
      int chunk = c8 + 2 * j;        // 0..7 chunks of 8 u16
      u16x8 v = *(const u16x8*)(&Ps[w][rowL * 136 + chunk * 8]);
      *(u16x8*)(outb + (size_t)grow * E_ + h * D_ + chunk * 8) = v;
    }
  }
}

extern "C" void kernel_launch(void* const* d_in, const int* in_sizes, int n_in,
                              void* d_out, int out_size, void* d_ws, size_t ws_size,
                              hipStream_t stream) {
  const void* x    = d_in[0];
  // d_in[1] physics_state: UNUSED — per-(b,h) scalar bias cancels in softmax.
  const void* mask = d_in[2];
  const void* Wq = d_in[3];
  const void* bq = d_in[4];
  const void* Wk = d_in[5];
  const void* bk = d_in[6];
  const void* Wv = d_in[7];
  const void* bv = d_in[8];
  const void* Wo = d_in[9];
  const void* bo = d_in[10];
  char* ws = (char*)d_ws;

  // ---- workspace plan (<= 24.1 MB). d_out (16 MB f32) doubles as scratch:
  // Qb bf16 in lower 8 MB, xc bf16 in upper 8 MB; both dead before the final
  // f32 GEMM overwrites d_out. ----
  const size_t MB = 1024 * 1024;
  u16* Kb   = (u16*)(ws + 0 * MB);          // 8 MB (B,H,T,D)
  u16* Vtb  = (u16*)(ws + 8 * MB);          // 8 MB (B,H,D,T)
  u16* Ab   = (u16*)(ws + 16 * MB);         // 8 MB attn out (B,T,E) bf16
  u16* WqT  = (u16*)(ws + 16 * MB);         // WqT|WkT|WvT contiguous 6 MB
  u16* WkT  = (u16*)(ws + 18 * MB);         //   (dead before attn writes Ab)
  u16* WvT  = (u16*)(ws + 20 * MB);
  u16* WoT  = (u16*)(ws + 0 * MB);          // over Kb, written after attn
  u16* bqc  = (u16*)(ws + 24 * MB);         // 4 bias slots, 2048 elems apart
  u16* boc  = bqc + 3 * 2048;
  float* mbg = (float*)(ws + 24 * MB + 64 * 1024);   // 16 KB
  int* flags = (int*)(ws + 24 * MB + 128 * 1024);

  u16* Qb = (u16*)d_out;                     // lower 8 MB of d_out
  u16* xc = (u16*)((char*)d_out + 8 * MB);   // upper 8 MB of d_out
  float* out = (float*)d_out;

  dim3 blk(256);
  const int NX = B_ * T_ * E_;     // 4M elems

  detect_kernel<<<1, blk, 0, stream>>>((const u16*)x, mask, flags);
  convf_kernel<<<NX / 8 / 256, blk, 0, stream>>>(x, xc, NX, flags);
  bias4_kernel<<<4, blk, 0, stream>>>(bq, bk, bv, bo, bqc, flags);
  maskbias_kernel<<<16, blk, 0, stream>>>(mask, mbg, flags);

  wtc_kernel<<<dim3(16, 16), blk, 0, stream>>>(Wq, WqT, flags);
  wtc_kernel<<<dim3(16, 16), blk, 0, stream>>>(Wk, WkT, flags);
  wtc_kernel<<<dim3(16, 16), blk, 0, stream>>>(Wv, WvT, flags);

  gemm_qkv_kernel<<<dim3(32, 24), blk, 0, stream>>>(xc, WqT, bqc, Qb, Kb, Vtb);
  attn_kernel<<<dim3(512), blk, 0, stream>>>(Qb, Kb, Vtb, mbg, Ab);
  wtc_kernel<<<dim3(16, 16), blk, 0, stream>>>(Wo, WoT, flags);  // Kb dead now
  gemm_out_kernel<<<dim3(32, 8), blk, 0, stream>>>(Ab, WoT, boc, out);
}

// Round 8
// 145.622 us; speedup vs baseline: 8.0653x; 1.0643x over previous
//
#include <hip/hip_runtime.h>
#include <hip/hip_bf16.h>
#include <stdint.h>

// Problem constants
#define E_  1024
#define H_  16
#define D_  64
#define T_  2048
#define B_  2

typedef unsigned short u16;
typedef unsigned char u8;
typedef __attribute__((ext_vector_type(8))) __bf16 bf16x8;
typedef __attribute__((ext_vector_type(4))) float f32x4;
typedef __attribute__((ext_vector_type(8))) u16 u16x8;
typedef __attribute__((ext_vector_type(4))) u16 u16x4;
typedef __attribute__((ext_vector_type(2))) uint32_t u32x2;

__device__ __forceinline__ float bf2f(u16 u) {
  union { uint32_t u32; float f; } x; x.u32 = ((uint32_t)u) << 16; return x.f;
}
__device__ __forceinline__ u16 f2bf(float v) {
  union { float f; uint32_t u; } x; x.f = v;
  uint32_t r = x.u + 0x7fffu + ((x.u >> 16) & 1u);  // round-to-nearest-even
  return (u16)(r >> 16);
}
__device__ __forceinline__ void async16(const void* g, void* l) {
  __builtin_amdgcn_global_load_lds(
      (const __attribute__((address_space(1))) void*)g,
      (__attribute__((address_space(3))) void*)l, 16, 0, 0);
}

// ---------------- dtype detection ----------------
__global__ __launch_bounds__(256) void detect_kernel(const u16* __restrict__ xu,
                                                     const void* __restrict__ mp,
                                                     int* __restrict__ flags) {
  __shared__ int cnt[2];
  const int tid = threadIdx.x;
  if (tid < 2) cnt[tid] = 0;
  __syncthreads();
  int c = 0;
  for (int i = tid; i < 4096; i += 256) {
    u16 u = xu[2 * i];
    int e = (u >> 7) & 0xFF;
    if (e != 0 && (e <= 0x40 || e >= 0xC0)) c++;
  }
  atomicAdd(&cnt[0], c);
  int m = 0;
  const unsigned int* mi = (const unsigned int*)mp;
  for (int i = tid; i < 1024; i += 256)
    if (mi[i] > 1u) m++;
  atomicAdd(&cnt[1], m);
  __syncthreads();
  if (tid == 0) {
    flags[0] = (cnt[0] > 409) ? 1 : 0;
    flags[1] = (cnt[1] == 0) ? 1 : 0;
  }
}

// canonicalize a float tensor (f32 or bf16 per flags[0]) to bf16
__global__ __launch_bounds__(256) void convf_kernel(const void* __restrict__ src,
                                                    u16* __restrict__ dst, int n,
                                                    const int* __restrict__ flags) {
  int i = (blockIdx.x * 256 + threadIdx.x) * 8;
  if (i >= n) return;
  if (flags[0]) {
    const float* s = (const float*)src;
    u16x8 o;
#pragma unroll
    for (int j = 0; j < 8; ++j) o[j] = f2bf(s[i + j]);
    *(u16x8*)(dst + i) = o;
  } else {
    *(u16x8*)(dst + i) = *(const u16x8*)((const u16*)src + i);
  }
}

// all four biases in one dispatch; dst slots spaced 2048 elems apart
__global__ __launch_bounds__(256) void bias4_kernel(
    const void* __restrict__ b0, const void* __restrict__ b1,
    const void* __restrict__ b2, const void* __restrict__ b3,
    u16* __restrict__ dst, const int* __restrict__ flags) {
  const void* src = (blockIdx.x == 0) ? b0 : (blockIdx.x == 1) ? b1
                    : (blockIdx.x == 2) ? b2 : b3;
  u16* d = dst + blockIdx.x * 2048;
  int t = threadIdx.x;
#pragma unroll
  for (int j = 0; j < 4; ++j) {
    int i = t + j * 256;
    d[i] = flags[0] ? f2bf(((const float*)src)[i]) : ((const u16*)src)[i];
  }
}

// mask -> log2-domain additive constant: keep -> -SH, drop -> -30000
__global__ __launch_bounds__(256) void maskbias_kernel(const void* __restrict__ mp,
                                                       float* __restrict__ mbg,
                                                       const int* __restrict__ flags) {
  int i = blockIdx.x * 256 + threadIdx.x;  // 4096 total
  int keep = flags[1] ? (((const int*)mp)[i] != 0) : (((const u8*)mp)[i] != 0);
  mbg[i] = keep ? -5.77078016f : -30000.f;   // -4*log2(e) | masked
}

// ------- fused weight convert(+f32->bf16) + transpose: WT[e][i] = W[i][e] ----
__global__ __launch_bounds__(256) void wtc_kernel(const void* __restrict__ Wv,
                                                  u16* __restrict__ WT,
                                                  const int* __restrict__ flags) {
  __shared__ __align__(16) u16 tile[64][65];
  const int bx = blockIdx.x * 64;   // source col block
  const int by = blockIdx.y * 64;   // source row block
  const int t = threadIdx.x;
  const int f32in = flags[0];
#pragma unroll
  for (int p = 0; p < 2; ++p) {
    int row = p * 32 + (t >> 3);
    int ch = t & 7;
    if (f32in) {
      const float* s = (const float*)Wv + (size_t)(by + row) * E_ + bx + ch * 8;
#pragma unroll
      for (int j = 0; j < 8; ++j) tile[row][ch * 8 + j] = f2bf(s[j]);
    } else {
      u16x8 v = *(const u16x8*)((const u16*)Wv + (size_t)(by + row) * E_ + bx + ch * 8);
#pragma unroll
      for (int j = 0; j < 8; ++j) tile[row][ch * 8 + j] = v[j];
    }
  }
  __syncthreads();
#pragma unroll
  for (int p = 0; p < 2; ++p) {
    int orow = p * 32 + (t >> 3);
    int ch = t & 7;
    u16x8 v;
#pragma unroll
    for (int j = 0; j < 8; ++j) v[j] = tile[ch * 8 + j][orow];
    *(u16x8*)(WT + (size_t)(bx + orow) * E_ + by + ch * 8) = v;
  }
}

// ---------------- fused QKV GEMM -------------------------------------------
// A: 4096x1024 bf16. BTm: 3072x1024 (WqT|WkT|WvT contiguous).
__global__ __launch_bounds__(256, 2) void gemm_qkv_kernel(
    const u16* __restrict__ A, const u16* __restrict__ BTm,
    const u16* __restrict__ biases, u16* __restrict__ Qb,
    u16* __restrict__ Kb, u16* __restrict__ Vtb) {
  __shared__ __align__(16) u16 As[128 * 64];
  __shared__ __align__(16) u16 Bs[128 * 64];
  const int tid = threadIdx.x, lane = tid & 63, wid = tid >> 6;
  const int wm = wid >> 1, wn = wid & 1;
  const int l15 = lane & 15, lg = lane >> 4;
  const int r0 = blockIdx.x * 128, c0 = blockIdx.y * 128;
  f32x4 acc[4][4] = {};

  for (int k0 = 0; k0 < E_; k0 += 64) {
    __syncthreads();
#pragma unroll
    for (int i = 0; i < 4; ++i) {
      int row = i * 32 + (tid >> 3);
      int g = (tid & 7) ^ (row & 7);  // inverse-swizzled global source (T2)
      async16(A + (size_t)(r0 + row) * E_ + k0 + g * 8,
              (char*)As + i * 4096 + tid * 16);
      async16(BTm + (size_t)(c0 + row) * E_ + k0 + g * 8,
              (char*)Bs + i * 4096 + tid * 16);
    }
    __syncthreads();
#pragma unroll
    for (int kk = 0; kk < 2; ++kk) {
      bf16x8 af[4], bfr[4];
#pragma unroll
      for (int mt = 0; mt < 4; ++mt) {
        int rowa = wm * 64 + mt * 16 + l15;
        int sa = (kk * 4 + lg) ^ (rowa & 7);
        af[mt] = *(const bf16x8*)((const char*)As + rowa * 128 + sa * 16);
        int rowb = wn * 64 + mt * 16 + l15;
        int sb = (kk * 4 + lg) ^ (rowb & 7);
        bfr[mt] = *(const bf16x8*)((const char*)Bs + rowb * 128 + sb * 16);
      }
#pragma unroll
      for (int mt = 0; mt < 4; ++mt)
#pragma unroll
        for (int nt = 0; nt < 4; ++nt)
          acc[mt][nt] = __builtin_amdgcn_mfma_f32_16x16x32_bf16(
              af[mt], bfr[nt], acc[mt][nt], 0, 0, 0);
    }
  }

  const int sel = c0 >> 10;           // 0=Q, 1=K, 2=V
  u16* outp = (sel == 0) ? Qb : Kb;
#pragma unroll
  for (int mt = 0; mt < 4; ++mt) {
#pragma unroll
    for (int nt = 0; nt < 4; ++nt) {
      int colG = c0 + wn * 64 + nt * 16 + l15;
      int colL = colG & 1023;
      float bv = bf2f(biases[sel * 2048 + colL]);
      int rbase = r0 + wm * 64 + mt * 16 + lg * 4;
      int hh = colL >> 6, dd = colL & 63;
      if (sel == 2) {  // V transposed (B,H,D,T), packed 8B stores
        int bb = rbase >> 11, t0 = rbase & (T_ - 1);
        u16x4 pk;
#pragma unroll
        for (int r = 0; r < 4; ++r) pk[r] = f2bf(acc[mt][nt][r] + bv);
        *(u16x4*)(Vtb + (size_t)((bb * H_ + hh) * D_ + dd) * T_ + t0) = pk;
      } else {         // Q/K (B,H,T,D)
#pragma unroll
        for (int r = 0; r < 4; ++r) {
          int row = rbase + r;
          int bb = row >> 11, t = row & (T_ - 1);
          outp[(size_t)((bb * H_ + hh) * T_ + t) * D_ + dd] =
              f2bf(acc[mt][nt][r] + bv);
        }
      }
    }
  }
}

// ---------------- final GEMM: f32 output -----------------------------------
__global__ __launch_bounds__(256, 2) void gemm_out_kernel(
    const u16* __restrict__ A, const u16* __restrict__ BTm,
    const u16* __restrict__ bias, float* __restrict__ out) {
  __shared__ __align__(16) u16 As[128 * 64];
  __shared__ __align__(16) u16 Bs[128 * 64];
  const int tid = threadIdx.x, lane = tid & 63, wid = tid >> 6;
  const int wm = wid >> 1, wn = wid & 1;
  const int l15 = lane & 15, lg = lane >> 4;
  const int r0 = blockIdx.x * 128, c0 = blockIdx.y * 128;
  f32x4 acc[4][4] = {};

  for (int k0 = 0; k0 < E_; k0 += 64) {
    __syncthreads();
#pragma unroll
    for (int i = 0; i < 4; ++i) {
      int row = i * 32 + (tid >> 3);
      int g = (tid & 7) ^ (row & 7);
      async16(A + (size_t)(r0 + row) * E_ + k0 + g * 8,
              (char*)As + i * 4096 + tid * 16);
      async16(BTm + (size_t)(c0 + row) * E_ + k0 + g * 8,
              (char*)Bs + i * 4096 + tid * 16);
    }
    __syncthreads();
#pragma unroll
    for (int kk = 0; kk < 2; ++kk) {
      bf16x8 af[4], bfr[4];
#pragma unroll
      for (int mt = 0; mt < 4; ++mt) {
        int rowa = wm * 64 + mt * 16 + l15;
        int sa = (kk * 4 + lg) ^ (rowa & 7);
        af[mt] = *(const bf16x8*)((const char*)As + rowa * 128 + sa * 16);
        int rowb = wn * 64 + mt * 16 + l15;
        int sb = (kk * 4 + lg) ^ (rowb & 7);
        bfr[mt] = *(const bf16x8*)((const char*)Bs + rowb * 128 + sb * 16);
      }
#pragma unroll
      for (int mt = 0; mt < 4; ++mt)
#pragma unroll
        for (int nt = 0; nt < 4; ++nt)
          acc[mt][nt] = __builtin_amdgcn_mfma_f32_16x16x32_bf16(
              af[mt], bfr[nt], acc[mt][nt], 0, 0, 0);
    }
  }

#pragma unroll
  for (int mt = 0; mt < 4; ++mt)
#pragma unroll
    for (int nt = 0; nt < 4; ++nt) {
      int col = c0 + wn * 64 + nt * 16 + l15;
      float bv = bf2f(bias[col]);
      int rbase = r0 + wm * 64 + mt * 16 + lg * 4;
#pragma unroll
      for (int r = 0; r < 4; ++r)
        out[(size_t)(rbase + r) * E_ + col] = acc[mt][nt][r] + bv;
    }
}

// ---------------- MFMA flash attention (swapped QK^T, packed P) -------------
// S^T = mfma(K,Q): lane holds P for q=col(l15), keys row=mf*16+lg*4+r —
// 4 consecutive keys/fragment -> cvt_pk + 8B LDS writes. P layout [q][key]
// unchanged for PV. Fixed-shift softmax in log2-domain; mask folded in mbg.
__global__ __launch_bounds__(256, 2) void attn_kernel(
    const u16* __restrict__ Q, const u16* __restrict__ K,
    const u16* __restrict__ VT, const float* __restrict__ mbg,
    u16* __restrict__ outb) {
  __shared__ __align__(16) u16 Ks[128 * 64];    // K tile [key][d], swizzled
  __shared__ __align__(16) u16 Vs[64 * 128];    // V^T tile [d][key], swizzled
  __shared__ __align__(16) u16 Ps[4][32 * 136]; // per-wave P, +8 pad
  __shared__ __align__(16) float mb[T_];        // log2-domain mask constant
  // XCD-local decode: all 16 q-blocks of a head land on one XCD (L2 reuse)
  const int wg = blockIdx.x;
  const int xcd = wg & 7, slot = wg >> 3;
  const int bh = xcd + 8 * (slot >> 4);
  const int q0 = (slot & 15) * 128;
  const int b = bh >> 4, h = bh & 15;
  const int tid = threadIdx.x, lane = tid & 63, w = tid >> 6;
  const int l15 = lane & 15, lg = lane >> 4;

  for (int i = tid; i < T_; i += 256) mb[i] = mbg[b * T_ + i];

  const u16* qb = Q + (size_t)bh * T_ * D_;
  const u16* kb = K + (size_t)bh * T_ * D_;
  const u16* vb = VT + (size_t)bh * D_ * T_;

  bf16x8 qf[2][2];  // Q hoisted: frag row=l15, k=kd*32+lg*8
#pragma unroll
  for (int mt = 0; mt < 2; ++mt)
#pragma unroll
    for (int kd = 0; kd < 2; ++kd) {
      int row = q0 + w * 32 + mt * 16 + l15;
      qf[mt][kd] = *(const bf16x8*)(qb + (size_t)row * D_ + kd * 32 + lg * 8);
    }

  f32x4 o[2][4] = {};
  float lrow[2] = {0.f, 0.f};       // per-lane sum for q = mt*16+l15
  const float cc = 0.125f * 1.44269504f;  // scale * log2(e)

  for (int kt = 0; kt < 16; ++kt) {
    const int kk0 = kt * 128;
    __syncthreads();
#pragma unroll
    for (int i = 0; i < 4; ++i) {   // K tile: 128 keys x 64 d
      int row = i * 32 + (tid >> 3);
      int g = (tid & 7) ^ (row & 7);
      async16(kb + (size_t)(kk0 + row) * D_ + g * 8,
              (char*)Ks + i * 4096 + tid * 16);
    }
#pragma unroll
    for (int i = 0; i < 4; ++i) {   // V^T tile: 64 d x 128 keys
      int row = i * 16 + (tid >> 4);
      int g = (tid & 15) ^ (row & 7);
      async16(vb + (size_t)row * T_ + kk0 + g * 8,
              (char*)Vs + i * 4096 + tid * 16);
    }
    __syncthreads();

    // S^T = K Q^T  (swapped operands; same fragment loads as before)
    f32x4 s2[2][8] = {};
#pragma unroll
    for (int kd = 0; kd < 2; ++kd) {
      bf16x8 kf[8];
#pragma unroll
      for (int mf = 0; mf < 8; ++mf) {
        int row = mf * 16 + l15;
        int slot2 = (kd * 4 + lg) ^ (row & 7);
        kf[mf] = *(const bf16x8*)((const char*)Ks + row * 128 + slot2 * 16);
      }
      __builtin_amdgcn_s_setprio(1);
#pragma unroll
      for (int mt = 0; mt < 2; ++mt)
#pragma unroll
        for (int mf = 0; mf < 8; ++mf)
          s2[mt][mf] = __builtin_amdgcn_mfma_f32_16x16x32_bf16(
              kf[mf], qf[mt][kd], s2[mt][mf], 0, 0, 0);
      __builtin_amdgcn_s_setprio(0);
    }

    // P = exp2(s*cc + mb), pack pairs, 8B LDS writes; per-lane row sums
#pragma unroll
    for (int mt = 0; mt < 2; ++mt) {
      float lr = 0.f;
#pragma unroll
      for (int mf = 0; mf < 8; ++mf) {
        f32x4 mb4 = *(const f32x4*)&mb[kk0 + mf * 16 + lg * 4];
        float p0 = exp2f(fmaf(s2[mt][mf][0], cc, mb4[0]));
        float p1 = exp2f(fmaf(s2[mt][mf][1], cc, mb4[1]));
        float p2 = exp2f(fmaf(s2[mt][mf][2], cc, mb4[2]));
        float p3 = exp2f(fmaf(s2[mt][mf][3], cc, mb4[3]));
        lr += (p0 + p1) + (p2 + p3);
        uint32_t w0, w1;
        asm("v_cvt_pk_bf16_f32 %0, %1, %2" : "=v"(w0) : "v"(p0), "v"(p1));
        asm("v_cvt_pk_bf16_f32 %0, %1, %2" : "=v"(w1) : "v"(p2), "v"(p3));
        u32x2 pk = {w0, w1};
        *(u32x2*)((char*)&Ps[w][0] + (mt * 16 + l15) * 272 + mf * 32 + lg * 8) = pk;
      }
      lrow[mt] += lr;
    }

    asm volatile("s_waitcnt lgkmcnt(0)" ::: "memory");  // P writes -> reads
    __builtin_amdgcn_sched_barrier(0);

    // O += P V  (k in 4 chunks of 32) — unchanged
#pragma unroll
    for (int kk = 0; kk < 4; ++kk) {
      bf16x8 pf[2], vf[4];
#pragma unroll
      for (int mt = 0; mt < 2; ++mt)
        pf[mt] = *(const bf16x8*)((const char*)&Ps[w][0] +
                                  (mt * 16 + l15) * 272 + kk * 64 + lg * 16);
#pragma unroll
      for (int df = 0; df < 4; ++df) {
        int row = df * 16 + l15;
        int slot2 = (kk * 4 + lg) ^ (row & 7);
        vf[df] = *(const bf16x8*)((const char*)Vs + row * 256 + slot2 * 16);
      }
      __builtin_amdgcn_s_setprio(1);
#pragma unroll
      for (int mt = 0; mt < 2; ++mt)
#pragma unroll
        for (int df = 0; df < 4; ++df)
          o[mt][df] = __builtin_amdgcn_mfma_f32_16x16x32_bf16(
              pf[mt], vf[df], o[mt][df], 0, 0, 0);
      __builtin_amdgcn_s_setprio(0);
    }
  }

  // l-reduction: lane's lrow[mt] covers its lg's 32 keys of q=mt*16+l15;
  // sum across lg (xor 16,32), then redistribute to epilogue's q=lg*4+r.
  float inv[2][4];
#pragma unroll
  for (int mt = 0; mt < 2; ++mt) {
    float t = lrow[mt];
    t += __shfl_xor(t, 16);
    t += __shfl_xor(t, 32);
    float ti = (t > 0.f) ? 1.0f / t : 0.f;
#pragma unroll
    for (int r = 0; r < 4; ++r)
      inv[mt][r] = __shfl(ti, (lane & 48) | (lg * 4 + r));
  }

  // stage o into Ps[w] (per-wave private), then vector-store 16B chunks
#pragma unroll
  for (int mt = 0; mt < 2; ++mt)
#pragma unroll
    for (int df = 0; df < 4; ++df)
#pragma unroll
      for (int r = 0; r < 4; ++r) {
        int prow = mt * 16 + lg * 4 + r;
        Ps[w][prow * 136 + df * 16 + l15] = f2bf(o[mt][df][r] * inv[mt][r]);
      }
  asm volatile("s_waitcnt lgkmcnt(0)" ::: "memory");
  __builtin_amdgcn_sched_barrier(0);
  {
    int rowL = lane >> 1;            // 0..31
    int c8 = lane & 1;               // chunk parity
    int grow = b * T_ + q0 + w * 32 + rowL;
#pragma unroll
    for (int j = 0; j < 4; ++j) {
      int chunk = c8 + 2 * j;        // 0..7 chunks of 8 u16
      u16x8 v = *(const u16x8*)(&Ps[w][rowL * 136 + chunk * 8]);
      *(u16x8*)(outb + (size_t)grow * E_ + h * D_ + chunk * 8) = v;
    }
  }
}

extern "C" void kernel_launch(void* const* d_in, const int* in_sizes, int n_in,
                              void* d_out, int out_size, void* d_ws, size_t ws_size,
                              hipStream_t stream) {
  const void* x    = d_in[0];
  // d_in[1] physics_state: UNUSED — per-(b,h) scalar bias cancels in softmax.
  const void* mask = d_in[2];
  const void* Wq = d_in[3];
  const void* bq = d_in[4];
  const void* Wk = d_in[5];
  const void* bk = d_in[6];
  const void* Wv = d_in[7];
  const void* bv = d_in[8];
  const void* Wo = d_in[9];
  const void* bo = d_in[10];
  char* ws = (char*)d_ws;

  // ---- workspace plan (<= 24.1 MB). d_out (16 MB f32) doubles as scratch:
  // Qb bf16 in lower 8 MB, xc bf16 in upper 8 MB; both dead before the final
  // f32 GEMM overwrites d_out. ----
  const size_t MB = 1024 * 1024;
  u16* Kb   = (u16*)(ws + 0 * MB);          // 8 MB (B,H,T,D)
  u16* Vtb  = (u16*)(ws + 8 * MB);          // 8 MB (B,H,D,T)
  u16* Ab   = (u16*)(ws + 16 * MB);         // 8 MB attn out (B,T,E) bf16
  u16* WqT  = (u16*)(ws + 16 * MB);         // WqT|WkT|WvT contiguous 6 MB
  u16* WkT  = (u16*)(ws + 18 * MB);         //   (dead before attn writes Ab)
  u16* WvT  = (u16*)(ws + 20 * MB);
  u16* WoT  = (u16*)(ws + 0 * MB);          // over Kb, written after attn
  u16* bqc  = (u16*)(ws + 24 * MB);         // 4 bias slots, 2048 elems apart
  u16* boc  = bqc + 3 * 2048;
  float* mbg = (float*)(ws + 24 * MB + 64 * 1024);   // 16 KB
  int* flags = (int*)(ws + 24 * MB + 128 * 1024);

  u16* Qb = (u16*)d_out;                     // lower 8 MB of d_out
  u16* xc = (u16*)((char*)d_out + 8 * MB);   // upper 8 MB of d_out
  float* out = (float*)d_out;

  dim3 blk(256);
  const int NX = B_ * T_ * E_;     // 4M elems

  detect_kernel<<<1, blk, 0, stream>>>((const u16*)x, mask, flags);
  convf_kernel<<<NX / 8 / 256, blk, 0, stream>>>(x, xc, NX, flags);
  bias4_kernel<<<4, blk, 0, stream>>>(bq, bk, bv, bo, bqc, flags);
  maskbias_kernel<<<16, blk, 0, stream>>>(mask, mbg, flags);

  wtc_kernel<<<dim3(16, 16), blk, 0, stream>>>(Wq, WqT, flags);
  wtc_kernel<<<dim3(16, 16), blk, 0, stream>>>(Wk, WkT, flags);
  wtc_kernel<<<dim3(16, 16), blk, 0, stream>>>(Wv, WvT, flags);

  gemm_qkv_kernel<<<dim3(32, 24), blk, 0, stream>>>(xc, WqT, bqc, Qb, Kb, Vtb);
  attn_kernel<<<dim3(512), blk, 0, stream>>>(Qb, Kb, Vtb, mbg, Ab);
  wtc_kernel<<<dim3(16, 16), blk, 0, stream>>>(Wo, WoT, flags);  // Kb dead now
  gemm_out_kernel<<<dim3(32, 8), blk, 0, stream>>>(Ab, WoT, boc, out);
}

// Round 9
// 136.444 us; speedup vs baseline: 8.6078x; 1.0673x over previous
//
#include <hip/hip_runtime.h>
#include <hip/hip_bf16.h>
#include <stdint.h>

// Problem constants
#define E_  1024
#define H_  16
#define D_  64
#define T_  2048
#define B_  2

typedef unsigned short u16;
typedef unsigned char u8;
typedef __attribute__((ext_vector_type(8))) __bf16 bf16x8;
typedef __attribute__((ext_vector_type(4))) float f32x4;
typedef __attribute__((ext_vector_type(8))) u16 u16x8;
typedef __attribute__((ext_vector_type(4))) u16 u16x4;
typedef __attribute__((ext_vector_type(2))) uint32_t u32x2;

__device__ __forceinline__ float bf2f(u16 u) {
  union { uint32_t u32; float f; } x; x.u32 = ((uint32_t)u) << 16; return x.f;
}
__device__ __forceinline__ u16 f2bf(float v) {
  union { float f; uint32_t u; } x; x.f = v;
  uint32_t r = x.u + 0x7fffu + ((x.u >> 16) & 1u);  // round-to-nearest-even
  return (u16)(r >> 16);
}
__device__ __forceinline__ void async16(const void* g, void* l) {
  __builtin_amdgcn_global_load_lds(
      (const __attribute__((address_space(1))) void*)g,
      (__attribute__((address_space(3))) void*)l, 16, 0, 0);
}

// Per-kernel dtype self-detection (wave-uniform): sample even u16 halves of
// the tensor's first 256B. bf16 data -> exponents ~[118,130], ~0 extreme.
// f32 data -> low mantissa halves, ~37-50% extreme. All-zero data -> count 0
// -> classified bf16 -> harmless (both decodings give zeros).
__device__ __forceinline__ int detect_f32(const void* src) {
  u16 u = ((const u16*)src)[2 * (threadIdx.x & 63)];
  int e = (u >> 7) & 0xFF;
  int ex = (e != 0 && (e <= 0x40 || e >= 0xC0)) ? 1 : 0;
  return __popcll(__ballot(ex)) > 16;
}

// canonicalize x to bf16
__global__ __launch_bounds__(256) void convf_kernel(const void* __restrict__ src,
                                                    u16* __restrict__ dst, int n) {
  const int f32in = detect_f32(src);
  int i = (blockIdx.x * 256 + threadIdx.x) * 8;
  if (i >= n) return;
  if (f32in) {
    const float* s = (const float*)src;
    u16x8 o;
#pragma unroll
    for (int j = 0; j < 8; ++j) o[j] = f2bf(s[i + j]);
    *(u16x8*)(dst + i) = o;
  } else {
    *(u16x8*)(dst + i) = *(const u16x8*)((const u16*)src + i);
  }
}

// all four biases in one dispatch; dst slots spaced 2048 elems apart
__global__ __launch_bounds__(256) void bias4_kernel(
    const void* __restrict__ b0, const void* __restrict__ b1,
    const void* __restrict__ b2, const void* __restrict__ b3,
    u16* __restrict__ dst) {
  const void* src = (blockIdx.x == 0) ? b0 : (blockIdx.x == 1) ? b1
                    : (blockIdx.x == 2) ? b2 : b3;
  const int f32in = detect_f32(src);
  u16* d = dst + blockIdx.x * 2048;
  int t = threadIdx.x;
#pragma unroll
  for (int j = 0; j < 4; ++j) {
    int i = t + j * 256;
    d[i] = f32in ? f2bf(((const float*)src)[i]) : ((const u16*)src)[i];
  }
}

// mask -> log2-domain additive constant: keep -> -SH, drop -> -30000
__global__ __launch_bounds__(256) void maskbias_kernel(const void* __restrict__ mp,
                                                       float* __restrict__ mbg) {
  unsigned w0 = ((const unsigned*)mp)[threadIdx.x & 63];
  int isInt = (__ballot(w0 > 1u) == 0ull);  // int32 bools are 0/1 only
  int i = blockIdx.x * 256 + threadIdx.x;   // 4096 total
  int keep = isInt ? (((const int*)mp)[i] != 0) : (((const u8*)mp)[i] != 0);
  mbg[i] = keep ? -5.77078016f : -30000.f;  // -4*log2(e) | masked
}

// fused weight convert + transpose, all 4 weights in one dispatch (z selects)
__global__ __launch_bounds__(256) void wtc4_kernel(
    const void* __restrict__ W0, const void* __restrict__ W1,
    const void* __restrict__ W2, const void* __restrict__ W3,
    u16* __restrict__ T0, u16* __restrict__ T1,
    u16* __restrict__ T2, u16* __restrict__ T3) {
  __shared__ __align__(16) u16 tile[64][65];
  const int z = blockIdx.z;
  const void* Wv = (z == 0) ? W0 : (z == 1) ? W1 : (z == 2) ? W2 : W3;
  u16* WT = (z == 0) ? T0 : (z == 1) ? T1 : (z == 2) ? T2 : T3;
  const int f32in = detect_f32(Wv);
  const int bx = blockIdx.x * 64, by = blockIdx.y * 64;
  const int t = threadIdx.x;
#pragma unroll
  for (int p = 0; p < 2; ++p) {
    int row = p * 32 + (t >> 3);
    int ch = t & 7;
    if (f32in) {
      const float* s = (const float*)Wv + (size_t)(by + row) * E_ + bx + ch * 8;
#pragma unroll
      for (int j = 0; j < 8; ++j) tile[row][ch * 8 + j] = f2bf(s[j]);
    } else {
      u16x8 v = *(const u16x8*)((const u16*)Wv + (size_t)(by + row) * E_ + bx + ch * 8);
#pragma unroll
      for (int j = 0; j < 8; ++j) tile[row][ch * 8 + j] = v[j];
    }
  }
  __syncthreads();
#pragma unroll
  for (int p = 0; p < 2; ++p) {
    int orow = p * 32 + (t >> 3);
    int ch = t & 7;
    u16x8 v;
#pragma unroll
    for (int j = 0; j < 8; ++j) v[j] = tile[ch * 8 + j][orow];
    *(u16x8*)(WT + (size_t)(bx + orow) * E_ + by + ch * 8) = v;
  }
}

// ---------------- fused QKV GEMM -------------------------------------------
__global__ __launch_bounds__(256, 2) void gemm_qkv_kernel(
    const u16* __restrict__ A, const u16* __restrict__ BTm,
    const u16* __restrict__ biases, u16* __restrict__ Qb,
    u16* __restrict__ Kb, u16* __restrict__ Vtb) {
  __shared__ __align__(16) u16 As[128 * 64];
  __shared__ __align__(16) u16 Bs[128 * 64];
  const int tid = threadIdx.x, lane = tid & 63, wid = tid >> 6;
  const int wm = wid >> 1, wn = wid & 1;
  const int l15 = lane & 15, lg = lane >> 4;
  const int r0 = blockIdx.x * 128, c0 = blockIdx.y * 128;
  f32x4 acc[4][4] = {};

  for (int k0 = 0; k0 < E_; k0 += 64) {
    __syncthreads();
#pragma unroll
    for (int i = 0; i < 4; ++i) {
      int row = i * 32 + (tid >> 3);
      int g = (tid & 7) ^ (row & 7);
      async16(A + (size_t)(r0 + row) * E_ + k0 + g * 8,
              (char*)As + i * 4096 + tid * 16);
      async16(BTm + (size_t)(c0 + row) * E_ + k0 + g * 8,
              (char*)Bs + i * 4096 + tid * 16);
    }
    __syncthreads();
#pragma unroll
    for (int kk = 0; kk < 2; ++kk) {
      bf16x8 af[4], bfr[4];
#pragma unroll
      for (int mt = 0; mt < 4; ++mt) {
        int rowa = wm * 64 + mt * 16 + l15;
        int sa = (kk * 4 + lg) ^ (rowa & 7);
        af[mt] = *(const bf16x8*)((const char*)As + rowa * 128 + sa * 16);
        int rowb = wn * 64 + mt * 16 + l15;
        int sb = (kk * 4 + lg) ^ (rowb & 7);
        bfr[mt] = *(const bf16x8*)((const char*)Bs + rowb * 128 + sb * 16);
      }
#pragma unroll
      for (int mt = 0; mt < 4; ++mt)
#pragma unroll
        for (int nt = 0; nt < 4; ++nt)
          acc[mt][nt] = __builtin_amdgcn_mfma_f32_16x16x32_bf16(
              af[mt], bfr[nt], acc[mt][nt], 0, 0, 0);
    }
  }

  const int sel = c0 >> 10;           // 0=Q, 1=K, 2=V
  u16* outp = (sel == 0) ? Qb : Kb;
#pragma unroll
  for (int mt = 0; mt < 4; ++mt) {
#pragma unroll
    for (int nt = 0; nt < 4; ++nt) {
      int colG = c0 + wn * 64 + nt * 16 + l15;
      int colL = colG & 1023;
      float bv = bf2f(biases[sel * 2048 + colL]);
      int rbase = r0 + wm * 64 + mt * 16 + lg * 4;
      int hh = colL >> 6, dd = colL & 63;
      if (sel == 2) {  // V transposed (B,H,D,T), packed 8B stores
        int bb = rbase >> 11, t0 = rbase & (T_ - 1);
        u16x4 pk;
#pragma unroll
        for (int r = 0; r < 4; ++r) pk[r] = f2bf(acc[mt][nt][r] + bv);
        *(u16x4*)(Vtb + (size_t)((bb * H_ + hh) * D_ + dd) * T_ + t0) = pk;
      } else {         // Q/K (B,H,T,D)
#pragma unroll
        for (int r = 0; r < 4; ++r) {
          int row = rbase + r;
          int bb = row >> 11, t = row & (T_ - 1);
          outp[(size_t)((bb * H_ + hh) * T_ + t) * D_ + dd] =
              f2bf(acc[mt][nt][r] + bv);
        }
      }
    }
  }
}

// ---------------- final GEMM: f32 output -----------------------------------
__global__ __launch_bounds__(256, 2) void gemm_out_kernel(
    const u16* __restrict__ A, const u16* __restrict__ BTm,
    const u16* __restrict__ bias, float* __restrict__ out) {
  __shared__ __align__(16) u16 As[128 * 64];
  __shared__ __align__(16) u16 Bs[128 * 64];
  const int tid = threadIdx.x, lane = tid & 63, wid = tid >> 6;
  const int wm = wid >> 1, wn = wid & 1;
  const int l15 = lane & 15, lg = lane >> 4;
  const int r0 = blockIdx.x * 128, c0 = blockIdx.y * 128;
  f32x4 acc[4][4] = {};

  for (int k0 = 0; k0 < E_; k0 += 64) {
    __syncthreads();
#pragma unroll
    for (int i = 0; i < 4; ++i) {
      int row = i * 32 + (tid >> 3);
      int g = (tid & 7) ^ (row & 7);
      async16(A + (size_t)(r0 + row) * E_ + k0 + g * 8,
              (char*)As + i * 4096 + tid * 16);
      async16(BTm + (size_t)(c0 + row) * E_ + k0 + g * 8,
              (char*)Bs + i * 4096 + tid * 16);
    }
    __syncthreads();
#pragma unroll
    for (int kk = 0; kk < 2; ++kk) {
      bf16x8 af[4], bfr[4];
#pragma unroll
      for (int mt = 0; mt < 4; ++mt) {
        int rowa = wm * 64 + mt * 16 + l15;
        int sa = (kk * 4 + lg) ^ (rowa & 7);
        af[mt] = *(const bf16x8*)((const char*)As + rowa * 128 + sa * 16);
        int rowb = wn * 64 + mt * 16 + l15;
        int sb = (kk * 4 + lg) ^ (rowb & 7);
        bfr[mt] = *(const bf16x8*)((const char*)Bs + rowb * 128 + sb * 16);
      }
#pragma unroll
      for (int mt = 0; mt < 4; ++mt)
#pragma unroll
        for (int nt = 0; nt < 4; ++nt)
          acc[mt][nt] = __builtin_amdgcn_mfma_f32_16x16x32_bf16(
              af[mt], bfr[nt], acc[mt][nt], 0, 0, 0);
    }
  }

#pragma unroll
  for (int mt = 0; mt < 4; ++mt)
#pragma unroll
    for (int nt = 0; nt < 4; ++nt) {
      int col = c0 + wn * 64 + nt * 16 + l15;
      float bv = bf2f(bias[col]);
      int rbase = r0 + wm * 64 + mt * 16 + lg * 4;
#pragma unroll
      for (int r = 0; r < 4; ++r)
        out[(size_t)(rbase + r) * E_ + col] = acc[mt][nt][r] + bv;
    }
}

// ---------------- MFMA flash attention (dbuf prefetch + fragment-Ps) --------
// KVBLK=64 tiles, double-buffered K/V: stage t+1 before compute of t; one
// barrier per tile (implicit vmcnt(0) = prefetch drain). Swapped QK^T; P is
// packed to bf16 and stored directly in PV A-fragment layout:
//   writer (mt,mf) key = mf*16+lg*4+r  ==  frag (kk=mf>>1) of receiver lane
//   (l15, lgr=(mf&1)*2+(lg>>1)), dwords 2*(lg&1)..+1. Write b64 + read b128
//   are both bank-conflict-free.
__global__ __launch_bounds__(256, 2) void attn_kernel(
    const u16* __restrict__ Q, const u16* __restrict__ K,
    const u16* __restrict__ VT, const float* __restrict__ mbg,
    u16* __restrict__ outb) {
  __shared__ __align__(16) u16 Ks[2][64 * 64];      // [buf][key][d] swizzled
  __shared__ __align__(16) u16 Vs[2][64 * 64];      // [buf][d][key] swizzled
  __shared__ __align__(16) u16 Ps[4][2][2][512];    // [w][mt][kk][lane*8]
  __shared__ __align__(16) float mb[T_];            // log2-domain mask bias
  // XCD-local decode: all 16 q-blocks of a head land on one XCD (L2 reuse)
  const int wg = blockIdx.x;
  const int xcd = wg & 7, slot = wg >> 3;
  const int bh = xcd + 8 * (slot >> 4);
  const int q0 = (slot & 15) * 128;
  const int b = bh >> 4, h = bh & 15;
  const int tid = threadIdx.x, lane = tid & 63, w = tid >> 6;
  const int l15 = lane & 15, lg = lane >> 4;

  for (int i = tid; i < T_; i += 256) mb[i] = mbg[b * T_ + i];

  const u16* qb = Q + (size_t)bh * T_ * D_;
  const u16* kb = K + (size_t)bh * T_ * D_;
  const u16* vb = VT + (size_t)bh * D_ * T_;

  bf16x8 qf[2][2];  // Q hoisted: B-frag col=l15(q), k=kd*32+lg*8
#pragma unroll
  for (int mt = 0; mt < 2; ++mt)
#pragma unroll
    for (int kd = 0; kd < 2; ++kd) {
      int row = q0 + w * 32 + mt * 16 + l15;
      qf[mt][kd] = *(const bf16x8*)(qb + (size_t)row * D_ + kd * 32 + lg * 8);
    }

#define STAGE(kt_, bi_)                                                  \
  do {                                                                   \
    _Pragma("unroll")                                                    \
    for (int c = 0; c < 2; ++c) {                                        \
      int row_ = c * 32 + (tid >> 3);                                    \
      int g_ = (tid & 7) ^ (row_ & 7);                                   \
      async16(kb + (size_t)((kt_) * 64 + row_) * D_ + g_ * 8,            \
              (char*)&Ks[bi_][0] + c * 4096 + tid * 16);                 \
      async16(vb + (size_t)row_ * T_ + (kt_) * 64 + g_ * 8,              \
              (char*)&Vs[bi_][0] + c * 4096 + tid * 16);                 \
    }                                                                    \
  } while (0)

  STAGE(0, 0);
  __syncthreads();   // drains vmcnt(0): tile 0 + mb ready

  f32x4 o[2][4] = {};
  float lrow[2] = {0.f, 0.f};
  const float cc = 0.125f * 1.44269504f;  // scale * log2(e)

  for (int kt = 0; kt < 32; ++kt) {
    const int cur = kt & 1;
    if (kt < 31) STAGE(kt + 1, cur ^ 1);  // prefetch, no wait
    const char* Kc = (const char*)&Ks[cur][0];
    const char* Vc = (const char*)&Vs[cur][0];
    const int kk0 = kt * 64;

    // S^T = K Q^T  (C: col=l15=q, row=lg*4+r in mf*16 = key)
    f32x4 s2[2][4] = {};
#pragma unroll
    for (int kd = 0; kd < 2; ++kd) {
      bf16x8 kf[4];
#pragma unroll
      for (int mf = 0; mf < 4; ++mf) {
        int row = mf * 16 + l15;
        int sl = (kd * 4 + lg) ^ (row & 7);
        kf[mf] = *(const bf16x8*)(Kc + row * 128 + sl * 16);
      }
      __builtin_amdgcn_s_setprio(1);
#pragma unroll
      for (int mt = 0; mt < 2; ++mt)
#pragma unroll
        for (int mf = 0; mf < 4; ++mf)
          s2[mt][mf] = __builtin_amdgcn_mfma_f32_16x16x32_bf16(
              kf[mf], qf[mt][kd], s2[mt][mf], 0, 0, 0);
      __builtin_amdgcn_s_setprio(0);
    }

    // P = exp2(s*cc + mb); pack to PV-fragment layout (conflict-free b64)
#pragma unroll
    for (int mt = 0; mt < 2; ++mt) {
#pragma unroll
      for (int mf = 0; mf < 4; ++mf) {
        f32x4 mb4 = *(const f32x4*)&mb[kk0 + mf * 16 + lg * 4];
        float p0 = exp2f(fmaf(s2[mt][mf][0], cc, mb4[0]));
        float p1 = exp2f(fmaf(s2[mt][mf][1], cc, mb4[1]));
        float p2 = exp2f(fmaf(s2[mt][mf][2], cc, mb4[2]));
        float p3 = exp2f(fmaf(s2[mt][mf][3], cc, mb4[3]));
        lrow[mt] += (p0 + p1) + (p2 + p3);
        uint32_t w0, w1;
        asm("v_cvt_pk_bf16_f32 %0, %1, %2" : "=v"(w0) : "v"(p0), "v"(p1));
        asm("v_cvt_pk_bf16_f32 %0, %1, %2" : "=v"(w1) : "v"(p2), "v"(p3));
        u32x2 pk = {w0, w1};
        int lgr = (mf & 1) * 2 + (lg >> 1);
        *(u32x2*)((char*)&Ps[w][mt][mf >> 1][0] +
                  (l15 + 16 * lgr) * 16 + 8 * (lg & 1)) = pk;
      }
    }

    asm volatile("s_waitcnt lgkmcnt(0)" ::: "memory");  // P writes -> reads
    __builtin_amdgcn_sched_barrier(0);

    // O += P V
#pragma unroll
    for (int kk = 0; kk < 2; ++kk) {
      bf16x8 pf[2], vf[4];
#pragma unroll
      for (int mt = 0; mt < 2; ++mt)
        pf[mt] = *(const bf16x8*)((const char*)&Ps[w][mt][kk][0] + lane * 16);
#pragma unroll
      for (int df = 0; df < 4; ++df) {
        int row = df * 16 + l15;
        int sl = (kk * 4 + lg) ^ (row & 7);
        vf[df] = *(const bf16x8*)(Vc + row * 128 + sl * 16);
      }
      __builtin_amdgcn_s_setprio(1);
#pragma unroll
      for (int mt = 0; mt < 2; ++mt)
#pragma unroll
        for (int df = 0; df < 4; ++df)
          o[mt][df] = __builtin_amdgcn_mfma_f32_16x16x32_bf16(
              pf[mt], vf[df], o[mt][df], 0, 0, 0);
      __builtin_amdgcn_s_setprio(0);
    }
    __syncthreads();  // implicit vmcnt(0): prefetch landed; all waves done cur
  }
#undef STAGE

  // l-reduction across lg groups, redistribute to epilogue rows
  float inv[2][4];
#pragma unroll
  for (int mt = 0; mt < 2; ++mt) {
    float t = lrow[mt];
    t += __shfl_xor(t, 16);
    t += __shfl_xor(t, 32);
    float ti = (t > 0.f) ? 1.0f / t : 0.f;
#pragma unroll
    for (int r = 0; r < 4; ++r)
      inv[mt][r] = __shfl(ti, (lane & 48) | (lg * 4 + r));
  }

  // epilogue: stage o via per-wave scratch (Ks/Vs dead, 144B stride), then
  // 16B vector stores to Ab
  char* wbase = ((w < 2) ? (char*)&Ks[0][0] : (char*)&Vs[0][0]) + (w & 1) * 4608;
#pragma unroll
  for (int mt = 0; mt < 2; ++mt)
#pragma unroll
    for (int df = 0; df < 4; ++df)
#pragma unroll
      for (int r = 0; r < 4; ++r) {
        int prow = mt * 16 + lg * 4 + r;
        *(u16*)(wbase + prow * 144 + (df * 16 + l15) * 2) =
            f2bf(o[mt][df][r] * inv[mt][r]);
      }
  asm volatile("s_waitcnt lgkmcnt(0)" ::: "memory");
  __builtin_amdgcn_sched_barrier(0);
  {
    int rowL = lane >> 1;
    int c8 = lane & 1;
    int grow = b * T_ + q0 + w * 32 + rowL;
#pragma unroll
    for (int j = 0; j < 4; ++j) {
      int chunk = c8 + 2 * j;
      u16x8 v = *(const u16x8*)(wbase + rowL * 144 + chunk * 16);
      *(u16x8*)(outb + (size_t)grow * E_ + h * D_ + chunk * 8) = v;
    }
  }
}

extern "C" void kernel_launch(void* const* d_in, const int* in_sizes, int n_in,
                              void* d_out, int out_size, void* d_ws, size_t ws_size,
                              hipStream_t stream) {
  const void* x    = d_in[0];
  // d_in[1] physics_state: UNUSED — per-(b,h) scalar bias cancels in softmax.
  const void* mask = d_in[2];
  const void* Wq = d_in[3];
  const void* bq = d_in[4];
  const void* Wk = d_in[5];
  const void* bk = d_in[6];
  const void* Wv = d_in[7];
  const void* bv = d_in[8];
  const void* Wo = d_in[9];
  const void* bo = d_in[10];
  char* ws = (char*)d_ws;

  // ---- workspace plan (~26.1 MB; rounds 3/4 ran fine at ~31 MB). d_out
  // (16 MB f32) doubles as scratch: Qb bf16 lower 8 MB, xc bf16 upper 8 MB;
  // both dead before the final f32 GEMM overwrites d_out. ----
  const size_t MB = 1024 * 1024;
  u16* Kb   = (u16*)(ws + 0 * MB);          // 8 MB (B,H,T,D)
  u16* Vtb  = (u16*)(ws + 8 * MB);          // 8 MB (B,H,D,T)
  u16* Ab   = (u16*)(ws + 16 * MB);         // 8 MB attn out (B,T,E) bf16
  u16* WqT  = (u16*)(ws + 16 * MB);         // WqT|WkT|WvT overlay Ab (dead
  u16* WkT  = (u16*)(ws + 18 * MB);         //  before attn writes Ab)
  u16* WvT  = (u16*)(ws + 20 * MB);
  u16* WoT  = (u16*)(ws + 24 * MB);         // own 2 MB (read by gemm_out)
  u16* bqc  = (u16*)(ws + 26 * MB);         // 4 bias slots, 2048 elems apart
  u16* boc  = bqc + 3 * 2048;
  float* mbg = (float*)(ws + 26 * MB + 32 * 1024);   // 16 KB
  // total: 26 MB + 48 KB

  u16* Qb = (u16*)d_out;                     // lower 8 MB of d_out
  u16* xc = (u16*)((char*)d_out + 8 * MB);   // upper 8 MB of d_out
  float* out = (float*)d_out;

  dim3 blk(256);
  const int NX = B_ * T_ * E_;     // 4M elems

  convf_kernel<<<NX / 8 / 256, blk, 0, stream>>>(x, xc, NX);
  bias4_kernel<<<4, blk, 0, stream>>>(bq, bk, bv, bo, bqc);
  maskbias_kernel<<<16, blk, 0, stream>>>(mask, mbg);
  wtc4_kernel<<<dim3(16, 16, 4), blk, 0, stream>>>(Wq, Wk, Wv, Wo,
                                                   WqT, WkT, WvT, WoT);
  gemm_qkv_kernel<<<dim3(32, 24), blk, 0, stream>>>(xc, WqT, bqc, Qb, Kb, Vtb);
  attn_kernel<<<dim3(512), blk, 0, stream>>>(Qb, Kb, Vtb, mbg, Ab);
  gemm_out_kernel<<<dim3(32, 8), blk, 0, stream>>>(Ab, WoT, boc, out);
}

// Round 10
// 128.956 us; speedup vs baseline: 9.1076x; 1.0581x over previous
//
#include <hip/hip_runtime.h>
#include <hip/hip_bf16.h>
#include <stdint.h>

// Problem constants
#define E_  1024
#define H_  16
#define D_  64
#define T_  2048
#define B_  2

typedef unsigned short u16;
typedef unsigned char u8;
typedef __attribute__((ext_vector_type(8))) __bf16 bf16x8;
typedef __attribute__((ext_vector_type(4))) float f32x4;
typedef __attribute__((ext_vector_type(8))) u16 u16x8;
typedef __attribute__((ext_vector_type(4))) u16 u16x4;

__device__ __forceinline__ float bf2f(u16 u) {
  union { uint32_t u32; float f; } x; x.u32 = ((uint32_t)u) << 16; return x.f;
}
__device__ __forceinline__ u16 f2bf(float v) {
  union { float f; uint32_t u; } x; x.f = v;
  uint32_t r = x.u + 0x7fffu + ((x.u >> 16) & 1u);  // round-to-nearest-even
  return (u16)(r >> 16);
}
__device__ __forceinline__ void async16(const void* g, void* l) {
  __builtin_amdgcn_global_load_lds(
      (const __attribute__((address_space(1))) void*)g,
      (__attribute__((address_space(3))) void*)l, 16, 0, 0);
}
// key permutation within a 64-key tile: LDS/MFMA k-order j for actual key k.
// j = {K5, K3, K2, K4, K1, K0}  (so producer P registers == PV A-fragment)
__device__ __forceinline__ int jperm(int k) {
  return (k & 35) | ((k & 12) << 1) | ((k & 16) >> 2);
}

// Per-kernel dtype self-detection (wave-uniform): sample even u16 halves of
// the tensor's first 256B. bf16 -> exponents ~[118,130]; f32 low-halves are
// mantissa bits -> ~37-50% extreme. All-zero -> bf16 path (harmless).
__device__ __forceinline__ int detect_f32(const void* src) {
  u16 u = ((const u16*)src)[2 * (threadIdx.x & 63)];
  int e = (u >> 7) & 0xFF;
  int ex = (e != 0 && (e <= 0x40 || e >= 0xC0)) ? 1 : 0;
  return __popcll(__ballot(ex)) > 16;
}

// canonicalize x to bf16
__global__ __launch_bounds__(256) void convf_kernel(const void* __restrict__ src,
                                                    u16* __restrict__ dst, int n) {
  const int f32in = detect_f32(src);
  int i = (blockIdx.x * 256 + threadIdx.x) * 8;
  if (i >= n) return;
  if (f32in) {
    const float* s = (const float*)src;
    u16x8 o;
#pragma unroll
    for (int j = 0; j < 8; ++j) o[j] = f2bf(s[i + j]);
    *(u16x8*)(dst + i) = o;
  } else {
    *(u16x8*)(dst + i) = *(const u16x8*)((const u16*)src + i);
  }
}

// all four biases in one dispatch; dst slots spaced 2048 elems apart
__global__ __launch_bounds__(256) void bias4_kernel(
    const void* __restrict__ b0, const void* __restrict__ b1,
    const void* __restrict__ b2, const void* __restrict__ b3,
    u16* __restrict__ dst) {
  const void* src = (blockIdx.x == 0) ? b0 : (blockIdx.x == 1) ? b1
                    : (blockIdx.x == 2) ? b2 : b3;
  const int f32in = detect_f32(src);
  u16* d = dst + blockIdx.x * 2048;
  int t = threadIdx.x;
#pragma unroll
  for (int j = 0; j < 4; ++j) {
    int i = t + j * 256;
    d[i] = f32in ? f2bf(((const float*)src)[i]) : ((const u16*)src)[i];
  }
}

// mask -> log2-domain additive constant: keep -> -SH, drop -> -30000
__global__ __launch_bounds__(256) void maskbias_kernel(const void* __restrict__ mp,
                                                       float* __restrict__ mbg) {
  unsigned w0 = ((const unsigned*)mp)[threadIdx.x & 63];
  int isInt = (__ballot(w0 > 1u) == 0ull);  // int32 bools are 0/1 only
  int i = blockIdx.x * 256 + threadIdx.x;   // 4096 total
  int keep = isInt ? (((const int*)mp)[i] != 0) : (((const u8*)mp)[i] != 0);
  mbg[i] = keep ? -5.77078016f : -30000.f;  // -4*log2(e) | masked
}

// fused weight convert + transpose, all 4 weights in one dispatch (z selects)
__global__ __launch_bounds__(256) void wtc4_kernel(
    const void* __restrict__ W0, const void* __restrict__ W1,
    const void* __restrict__ W2, const void* __restrict__ W3,
    u16* __restrict__ T0, u16* __restrict__ T1,
    u16* __restrict__ T2, u16* __restrict__ T3) {
  __shared__ __align__(16) u16 tile[64][65];
  const int z = blockIdx.z;
  const void* Wv = (z == 0) ? W0 : (z == 1) ? W1 : (z == 2) ? W2 : W3;
  u16* WT = (z == 0) ? T0 : (z == 1) ? T1 : (z == 2) ? T2 : T3;
  const int f32in = detect_f32(Wv);
  const int bx = blockIdx.x * 64, by = blockIdx.y * 64;
  const int t = threadIdx.x;
#pragma unroll
  for (int p = 0; p < 2; ++p) {
    int row = p * 32 + (t >> 3);
    int ch = t & 7;
    if (f32in) {
      const float* s = (const float*)Wv + (size_t)(by + row) * E_ + bx + ch * 8;
#pragma unroll
      for (int j = 0; j < 8; ++j) tile[row][ch * 8 + j] = f2bf(s[j]);
    } else {
      u16x8 v = *(const u16x8*)((const u16*)Wv + (size_t)(by + row) * E_ + bx + ch * 8);
#pragma unroll
      for (int j = 0; j < 8; ++j) tile[row][ch * 8 + j] = v[j];
    }
  }
  __syncthreads();
#pragma unroll
  for (int p = 0; p < 2; ++p) {
    int orow = p * 32 + (t >> 3);
    int ch = t & 7;
    u16x8 v;
#pragma unroll
    for (int j = 0; j < 8; ++j) v[j] = tile[ch * 8 + j][orow];
    *(u16x8*)(WT + (size_t)(bx + orow) * E_ + by + ch * 8) = v;
  }
}

// ---------------- fused QKV GEMM -------------------------------------------
// V^T is stored with jperm-permuted t-order within each 64-key block so the
// attention PV B-operand matches the in-register P fragments.
__global__ __launch_bounds__(256, 2) void gemm_qkv_kernel(
    const u16* __restrict__ A, const u16* __restrict__ BTm,
    const u16* __restrict__ biases, u16* __restrict__ Qb,
    u16* __restrict__ Kb, u16* __restrict__ Vtb) {
  __shared__ __align__(16) u16 As[128 * 64];
  __shared__ __align__(16) u16 Bs[128 * 64];
  const int tid = threadIdx.x, lane = tid & 63, wid = tid >> 6;
  const int wm = wid >> 1, wn = wid & 1;
  const int l15 = lane & 15, lg = lane >> 4;
  const int r0 = blockIdx.x * 128, c0 = blockIdx.y * 128;
  f32x4 acc[4][4] = {};

  for (int k0 = 0; k0 < E_; k0 += 64) {
    __syncthreads();
#pragma unroll
    for (int i = 0; i < 4; ++i) {
      int row = i * 32 + (tid >> 3);
      int g = (tid & 7) ^ (row & 7);
      async16(A + (size_t)(r0 + row) * E_ + k0 + g * 8,
              (char*)As + i * 4096 + tid * 16);
      async16(BTm + (size_t)(c0 + row) * E_ + k0 + g * 8,
              (char*)Bs + i * 4096 + tid * 16);
    }
    __syncthreads();
#pragma unroll
    for (int kk = 0; kk < 2; ++kk) {
      bf16x8 af[4], bfr[4];
#pragma unroll
      for (int mt = 0; mt < 4; ++mt) {
        int rowa = wm * 64 + mt * 16 + l15;
        int sa = (kk * 4 + lg) ^ (rowa & 7);
        af[mt] = *(const bf16x8*)((const char*)As + rowa * 128 + sa * 16);
        int rowb = wn * 64 + mt * 16 + l15;
        int sb = (kk * 4 + lg) ^ (rowb & 7);
        bfr[mt] = *(const bf16x8*)((const char*)Bs + rowb * 128 + sb * 16);
      }
#pragma unroll
      for (int mt = 0; mt < 4; ++mt)
#pragma unroll
        for (int nt = 0; nt < 4; ++nt)
          acc[mt][nt] = __builtin_amdgcn_mfma_f32_16x16x32_bf16(
              af[mt], bfr[nt], acc[mt][nt], 0, 0, 0);
    }
  }

  const int sel = c0 >> 10;           // 0=Q, 1=K, 2=V
  u16* outp = (sel == 0) ? Qb : Kb;
#pragma unroll
  for (int mt = 0; mt < 4; ++mt) {
#pragma unroll
    for (int nt = 0; nt < 4; ++nt) {
      int colG = c0 + wn * 64 + nt * 16 + l15;
      int colL = colG & 1023;
      float bv = bf2f(biases[sel * 2048 + colL]);
      int rbase = r0 + wm * 64 + mt * 16 + lg * 4;
      int hh = colL >> 6, dd = colL & 63;
      if (sel == 2) {  // V^T (B,H,D,T) with jperm'd t within 64-blocks
        int bb = rbase >> 11, t0 = rbase & (T_ - 1);
        int tp = (t0 & ~63) | jperm(t0 & 63);   // low 2 bits preserved
        u16x4 pk;
#pragma unroll
        for (int r = 0; r < 4; ++r) pk[r] = f2bf(acc[mt][nt][r] + bv);
        *(u16x4*)(Vtb + (size_t)((bb * H_ + hh) * D_ + dd) * T_ + tp) = pk;
      } else {         // Q/K (B,H,T,D)
#pragma unroll
        for (int r = 0; r < 4; ++r) {
          int row = rbase + r;
          int bb = row >> 11, t = row & (T_ - 1);
          outp[(size_t)((bb * H_ + hh) * T_ + t) * D_ + dd] =
              f2bf(acc[mt][nt][r] + bv);
        }
      }
    }
  }
}

// ---------------- final GEMM: f32 output -----------------------------------
__global__ __launch_bounds__(256, 2) void gemm_out_kernel(
    const u16* __restrict__ A, const u16* __restrict__ BTm,
    const u16* __restrict__ bias, float* __restrict__ out) {
  __shared__ __align__(16) u16 As[128 * 64];
  __shared__ __align__(16) u16 Bs[128 * 64];
  const int tid = threadIdx.x, lane = tid & 63, wid = tid >> 6;
  const int wm = wid >> 1, wn = wid & 1;
  const int l15 = lane & 15, lg = lane >> 4;
  const int r0 = blockIdx.x * 128, c0 = blockIdx.y * 128;
  f32x4 acc[4][4] = {};

  for (int k0 = 0; k0 < E_; k0 += 64) {
    __syncthreads();
#pragma unroll
    for (int i = 0; i < 4; ++i) {
      int row = i * 32 + (tid >> 3);
      int g = (tid & 7) ^ (row & 7);
      async16(A + (size_t)(r0 + row) * E_ + k0 + g * 8,
              (char*)As + i * 4096 + tid * 16);
      async16(BTm + (size_t)(c0 + row) * E_ + k0 + g * 8,
              (char*)Bs + i * 4096 + tid * 16);
    }
    __syncthreads();
#pragma unroll
    for (int kk = 0; kk < 2; ++kk) {
      bf16x8 af[4], bfr[4];
#pragma unroll
      for (int mt = 0; mt < 4; ++mt) {
        int rowa = wm * 64 + mt * 16 + l15;
        int sa = (kk * 4 + lg) ^ (rowa & 7);
        af[mt] = *(const bf16x8*)((const char*)As + rowa * 128 + sa * 16);
        int rowb = wn * 64 + mt * 16 + l15;
        int sb = (kk * 4 + lg) ^ (rowb & 7);
        bfr[mt] = *(const bf16x8*)((const char*)Bs + rowb * 128 + sb * 16);
      }
#pragma unroll
      for (int mt = 0; mt < 4; ++mt)
#pragma unroll
        for (int nt = 0; nt < 4; ++nt)
          acc[mt][nt] = __builtin_amdgcn_mfma_f32_16x16x32_bf16(
              af[mt], bfr[nt], acc[mt][nt], 0, 0, 0);
    }
  }

#pragma unroll
  for (int mt = 0; mt < 4; ++mt)
#pragma unroll
    for (int nt = 0; nt < 4; ++nt) {
      int col = c0 + wn * 64 + nt * 16 + l15;
      float bv = bf2f(bias[col]);
      int rbase = r0 + wm * 64 + mt * 16 + lg * 4;
#pragma unroll
      for (int r = 0; r < 4; ++r)
        out[(size_t)(rbase + r) * E_ + col] = acc[mt][nt][r] + bv;
    }
}

// ---------------- MFMA flash attention (P fully in registers) ---------------
// Swapped QK^T producer fragments, packed via cvt_pk, ARE the PV A-operand
// because V's key axis is jperm-permuted at generation time. No P LDS, no
// lgkmcnt fence. Mask bias read from global (L2-hot). LDS = K/V dbuf only.
__global__ __launch_bounds__(256, 2) void attn_kernel(
    const u16* __restrict__ Q, const u16* __restrict__ K,
    const u16* __restrict__ VT, const float* __restrict__ mbg,
    u16* __restrict__ outb) {
  __shared__ __align__(16) u16 Ks[2][64 * 64];      // [buf][key][d] swizzled
  __shared__ __align__(16) u16 Vs[2][64 * 64];      // [buf][d][key-perm] swz
  // XCD-local decode: all 16 q-blocks of a head land on one XCD (L2 reuse)
  const int wg = blockIdx.x;
  const int xcd = wg & 7, slot = wg >> 3;
  const int bh = xcd + 8 * (slot >> 4);
  const int q0 = (slot & 15) * 128;
  const int b = bh >> 4, h = bh & 15;
  const int tid = threadIdx.x, lane = tid & 63, w = tid >> 6;
  const int l15 = lane & 15, lg = lane >> 4;

  const u16* qb = Q + (size_t)bh * T_ * D_;
  const u16* kb = K + (size_t)bh * T_ * D_;
  const u16* vb = VT + (size_t)bh * D_ * T_;
  const float* mbb = mbg + b * T_ + lg * 4;   // per-lane mask-bias base

  bf16x8 qf[2][2];  // Q hoisted: B-frag col=l15(q), k=kd*32+lg*8
#pragma unroll
  for (int mt = 0; mt < 2; ++mt)
#pragma unroll
    for (int kd = 0; kd < 2; ++kd) {
      int row = q0 + w * 32 + mt * 16 + l15;
      qf[mt][kd] = *(const bf16x8*)(qb + (size_t)row * D_ + kd * 32 + lg * 8);
    }

#define STAGE(kt_, bi_)                                                  \
  do {                                                                   \
    _Pragma("unroll")                                                    \
    for (int c = 0; c < 2; ++c) {                                        \
      int row_ = c * 32 + (tid >> 3);                                    \
      int g_ = (tid & 7) ^ (row_ & 7);                                   \
      async16(kb + (size_t)((kt_) * 64 + row_) * D_ + g_ * 8,            \
              (char*)&Ks[bi_][0] + c * 4096 + tid * 16);                 \
      async16(vb + (size_t)row_ * T_ + (kt_) * 64 + g_ * 8,              \
              (char*)&Vs[bi_][0] + c * 4096 + tid * 16);                 \
    }                                                                    \
  } while (0)

  STAGE(0, 0);
  __syncthreads();   // drains vmcnt(0): tile 0 ready

  f32x4 o[2][4] = {};
  float lrow[2] = {0.f, 0.f};
  const float cc = 0.125f * 1.44269504f;  // scale * log2(e)

  for (int kt = 0; kt < 32; ++kt) {
    const int cur = kt & 1;
    if (kt < 31) STAGE(kt + 1, cur ^ 1);  // prefetch, no wait
    const char* Kc = (const char*)&Ks[cur][0];
    const char* Vc = (const char*)&Vs[cur][0];

    // mask bias for this tile (global, L2-hot; latency hides under QK^T)
    f32x4 mbv4[4];
#pragma unroll
    for (int mf = 0; mf < 4; ++mf)
      mbv4[mf] = *(const f32x4*)(mbb + kt * 64 + mf * 16);

    // S^T = K Q^T  (C: col=l15=q, row=mf*16+lg*4+r = key)
    f32x4 s2[2][4] = {};
#pragma unroll
    for (int kd = 0; kd < 2; ++kd) {
      bf16x8 kf[4];
#pragma unroll
      for (int mf = 0; mf < 4; ++mf) {
        int row = mf * 16 + l15;
        int sl = (kd * 4 + lg) ^ (row & 7);
        kf[mf] = *(const bf16x8*)(Kc + row * 128 + sl * 16);
      }
      __builtin_amdgcn_s_setprio(1);
#pragma unroll
      for (int mt = 0; mt < 2; ++mt)
#pragma unroll
        for (int mf = 0; mf < 4; ++mf)
          s2[mt][mf] = __builtin_amdgcn_mfma_f32_16x16x32_bf16(
              kf[mf], qf[mt][kd], s2[mt][mf], 0, 0, 0);
      __builtin_amdgcn_s_setprio(0);
    }

    // P = exp2(s*cc + mb), packed to bf16 pairs — stays in registers
    uint32_t pkw[2][4][2];
#pragma unroll
    for (int mt = 0; mt < 2; ++mt) {
#pragma unroll
      for (int mf = 0; mf < 4; ++mf) {
        float p0 = exp2f(fmaf(s2[mt][mf][0], cc, mbv4[mf][0]));
        float p1 = exp2f(fmaf(s2[mt][mf][1], cc, mbv4[mf][1]));
        float p2 = exp2f(fmaf(s2[mt][mf][2], cc, mbv4[mf][2]));
        float p3 = exp2f(fmaf(s2[mt][mf][3], cc, mbv4[mf][3]));
        lrow[mt] += (p0 + p1) + (p2 + p3);
        asm("v_cvt_pk_bf16_f32 %0, %1, %2" : "=v"(pkw[mt][mf][0]) : "v"(p0), "v"(p1));
        asm("v_cvt_pk_bf16_f32 %0, %1, %2" : "=v"(pkw[mt][mf][1]) : "v"(p2), "v"(p3));
      }
    }

    // O += P V : A-frag = {w0,w1 of mf=2kk, w0,w1 of mf=2kk+1} (in-lane!)
#pragma unroll
    for (int kk = 0; kk < 2; ++kk) {
      bf16x8 pf[2], vf[4];
#pragma unroll
      for (int mt = 0; mt < 2; ++mt) {
        union { uint32_t u[4]; bf16x8 v; } pu;
        pu.u[0] = pkw[mt][2 * kk][0];
        pu.u[1] = pkw[mt][2 * kk][1];
        pu.u[2] = pkw[mt][2 * kk + 1][0];
        pu.u[3] = pkw[mt][2 * kk + 1][1];
        pf[mt] = pu.v;
      }
#pragma unroll
      for (int df = 0; df < 4; ++df) {
        int row = df * 16 + l15;
        int sl = (kk * 4 + lg) ^ (row & 7);
        vf[df] = *(const bf16x8*)(Vc + row * 128 + sl * 16);
      }
      __builtin_amdgcn_s_setprio(1);
#pragma unroll
      for (int mt = 0; mt < 2; ++mt)
#pragma unroll
        for (int df = 0; df < 4; ++df)
          o[mt][df] = __builtin_amdgcn_mfma_f32_16x16x32_bf16(
              pf[mt], vf[df], o[mt][df], 0, 0, 0);
      __builtin_amdgcn_s_setprio(0);
    }
    __syncthreads();  // implicit vmcnt(0): prefetch landed; all waves done cur
  }
#undef STAGE

  // l-reduction across lg groups, redistribute to epilogue rows
  float inv[2][4];
#pragma unroll
  for (int mt = 0; mt < 2; ++mt) {
    float t = lrow[mt];
    t += __shfl_xor(t, 16);
    t += __shfl_xor(t, 32);
    float ti = (t > 0.f) ? 1.0f / t : 0.f;
#pragma unroll
    for (int r = 0; r < 4; ++r)
      inv[mt][r] = __shfl(ti, (lane & 48) | (lg * 4 + r));
  }

  // epilogue: stage o via per-wave LDS scratch (K/V dead), 16B stores to Ab
  char* wbase = ((w < 2) ? (char*)&Ks[0][0] : (char*)&Vs[0][0]) + (w & 1) * 4608;
#pragma unroll
  for (int mt = 0; mt < 2; ++mt)
#pragma unroll
    for (int df = 0; df < 4; ++df)
#pragma unroll
      for (int r = 0; r < 4; ++r) {
        int prow = mt * 16 + lg * 4 + r;
        *(u16*)(wbase + prow * 144 + (df * 16 + l15) * 2) =
            f2bf(o[mt][df][r] * inv[mt][r]);
      }
  asm volatile("s_waitcnt lgkmcnt(0)" ::: "memory");
  __builtin_amdgcn_sched_barrier(0);
  {
    int rowL = lane >> 1;
    int c8 = lane & 1;
    int grow = b * T_ + q0 + w * 32 + rowL;
#pragma unroll
    for (int j = 0; j < 4; ++j) {
      int chunk = c8 + 2 * j;
      u16x8 v = *(const u16x8*)(wbase + rowL * 144 + chunk * 16);
      *(u16x8*)(outb + (size_t)grow * E_ + h * D_ + chunk * 8) = v;
    }
  }
}

extern "C" void kernel_launch(void* const* d_in, const int* in_sizes, int n_in,
                              void* d_out, int out_size, void* d_ws, size_t ws_size,
                              hipStream_t stream) {
  const void* x    = d_in[0];
  // d_in[1] physics_state: UNUSED — per-(b,h) scalar bias cancels in softmax.
  const void* mask = d_in[2];
  const void* Wq = d_in[3];
  const void* bq = d_in[4];
  const void* Wk = d_in[5];
  const void* bk = d_in[6];
  const void* Wv = d_in[7];
  const void* bv = d_in[8];
  const void* Wo = d_in[9];
  const void* bo = d_in[10];
  char* ws = (char*)d_ws;

  // ---- workspace plan (~26.1 MB). d_out (16 MB f32) doubles as scratch:
  // Qb bf16 lower 8 MB, xc bf16 upper 8 MB; both dead before the final
  // f32 GEMM overwrites d_out. ----
  const size_t MB = 1024 * 1024;
  u16* Kb   = (u16*)(ws + 0 * MB);          // 8 MB (B,H,T,D)
  u16* Vtb  = (u16*)(ws + 8 * MB);          // 8 MB (B,H,D,T) key-permuted
  u16* Ab   = (u16*)(ws + 16 * MB);         // 8 MB attn out (B,T,E) bf16
  u16* WqT  = (u16*)(ws + 16 * MB);         // WqT|WkT|WvT overlay Ab (dead
  u16* WkT  = (u16*)(ws + 18 * MB);         //  before attn writes Ab)
  u16* WvT  = (u16*)(ws + 20 * MB);
  u16* WoT  = (u16*)(ws + 24 * MB);         // own 2 MB (read by gemm_out)
  u16* bqc  = (u16*)(ws + 26 * MB);         // 4 bias slots, 2048 elems apart
  u16* boc  = bqc + 3 * 2048;
  float* mbg = (float*)(ws + 26 * MB + 32 * 1024);   // 16 KB

  u16* Qb = (u16*)d_out;                     // lower 8 MB of d_out
  u16* xc = (u16*)((char*)d_out + 8 * MB);   // upper 8 MB of d_out
  float* out = (float*)d_out;

  dim3 blk(256);
  const int NX = B_ * T_ * E_;     // 4M elems

  convf_kernel<<<NX / 8 / 256, blk, 0, stream>>>(x, xc, NX);
  bias4_kernel<<<4, blk, 0, stream>>>(bq, bk, bv, bo, bqc);
  maskbias_kernel<<<16, blk, 0, stream>>>(mask, mbg);
  wtc4_kernel<<<dim3(16, 16, 4), blk, 0, stream>>>(Wq, Wk, Wv, Wo,
                                                   WqT, WkT, WvT, WoT);
  gemm_qkv_kernel<<<dim3(32, 24), blk, 0, stream>>>(xc, WqT, bqc, Qb, Kb, Vtb);
  attn_kernel<<<dim3(512), blk, 0, stream>>>(Qb, Kb, Vtb, mbg, Ab);
  gemm_out_kernel<<<dim3(32, 8), blk, 0, stream>>>(Ab, WoT, boc, out);
}